// Round 10
// baseline (369.276 us; speedup 1.0000x reference)
//
#include <hip/hip_runtime.h>
#include <hip/hip_bf16.h>
#include <hip/hip_fp8.h>
#include <math.h>

#define N_NODES 50000
#define N_EDGES 800000
#define SLOT_CAP 96                     // max in-degree slots per node (E[deg]=16, max<~50)
#define AGG_BLOCKS (N_NODES / 4)        // 12500 aggregate blocks (4 nodes each)

typedef __attribute__((ext_vector_type(8))) short short8;   // 8 x bf16 (4 VGPRs)
typedef __attribute__((ext_vector_type(4))) float f32x4;    // MFMA accumulator
typedef __attribute__((ext_vector_type(2))) float f32x2;

// ---------- device helpers ----------
__device__ __forceinline__ float selu_f(float x) {
    const float scale = 1.0507009873554805f;
    const float alpha = 1.6732632423543772f;
    return x > 0.f ? scale * x : scale * alpha * (expf(x) - 1.f);
}
__device__ __forceinline__ float lrelu_f(float x) {
    return x >= 0.f ? x : 0.2f * x;
}
__device__ __forceinline__ ushort f2bf(float f) {
    __hip_bfloat16 h = __float2bfloat16(f);   // RNE
    return *(ushort*)&h;
}
__device__ __forceinline__ unsigned char f2fp8(float f) {
    __hip_fp8_e4m3 q(f);                       // OCP e4m3, RNE+sat
    return (unsigned char)q.__x;
}
__device__ __forceinline__ float fp82f(unsigned char b) {
    __hip_fp8_e4m3 q; q.__x = (__hip_fp8_storage_t)b;
    return (float)q;
}
// decode 4 packed fp8 (one dword) -> 4 floats
__device__ __forceinline__ void fp8x4_decode(unsigned u, float* o) {
#if __has_builtin(__builtin_amdgcn_cvt_pk_f32_fp8)
    f32x2 lo = __builtin_amdgcn_cvt_pk_f32_fp8((int)u, false);
    f32x2 hi = __builtin_amdgcn_cvt_pk_f32_fp8((int)u, true);
    o[0] = lo.x; o[1] = lo.y; o[2] = hi.x; o[3] = hi.y;
#else
    o[0] = fp82f(u & 0xff);
    o[1] = fp82f((u >> 8) & 0xff);
    o[2] = fp82f((u >> 16) & 0xff);
    o[3] = fp82f(u >> 24);
#endif
}

// ---------- fused pack + init (once per call) ----------
__global__ void pack_all(const float* __restrict__ x, ushort* __restrict__ Apx,
                         const float* __restrict__ W1, ushort* __restrict__ Bp1,
                         const float* __restrict__ W2, ushort* __restrict__ Bp2,
                         int* __restrict__ cursor, float* __restrict__ g) {
    int i = blockIdx.x * blockDim.x + threadIdx.x;
    if (i < N_NODES * 128 / 8) {
        const float4* p = (const float4*)x + (size_t)i * 2;
        float4 a = p[0], b = p[1];
        ushort u[8] = { f2bf(a.x), f2bf(a.y), f2bf(a.z), f2bf(a.w),
                        f2bf(b.x), f2bf(b.y), f2bf(b.z), f2bf(b.w) };
        *(uint4*)(Apx + (size_t)i * 8) = *(uint4*)u;
    }
    if (i < 16 * 256) {                     // W1: K8 = 16
        int kg = i >> 8, n = i & 255;
        ushort u[8];
#pragma unroll
        for (int j = 0; j < 8; j++) u[j] = f2bf(W1[(size_t)(kg * 8 + j) * 256 + n]);
        *(uint4*)(Bp1 + ((size_t)kg * 256 + n) * 8) = *(uint4*)u;
    }
    if (i < 32 * 256) {                     // W2: K8 = 32
        int kg = i >> 8, n = i & 255;
        ushort u[8];
#pragma unroll
        for (int j = 0; j < 8; j++) u[j] = f2bf(W2[(size_t)(kg * 8 + j) * 256 + n]);
        *(uint4*)(Bp2 + ((size_t)kg * 256 + n) * 8) = *(uint4*)u;
    }
    if (i < N_NODES) cursor[i] = 0;
    if (i < 256) g[i] = 0.f;
}

// ---------- slot-CSR build: single pass (hist+scan+scatter collapsed) ----------
__global__ void edge_scatter(const int* __restrict__ tgt, const int* __restrict__ src,
                             int* __restrict__ cursor, int* __restrict__ ssrc, int E) {
    int e = blockIdx.x * blockDim.x + threadIdx.x;
    if (e >= E) return;
    int t = tgt[e];
    int r = atomicAdd(&cursor[t], 1);
    if (r < SLOT_CAP) ssrc[(size_t)t * SLOT_CAP + r] = src[e];
}

// ---------- MFMA GEMM (64-row block, 4x4 acc/wave) + fused scores ----------
// block = 256 thr = 4 waves; block tile 64 rows x 256 cols; wave wv owns all 64
// rows x cols wv*64..+63 == head wv. 16 MFMA : 8 loads per 32-k step.
// Fragment layouts (guide §3, m89/m91-verified): A[m=lane&15][k=quad*8+j],
// B[k=quad*8+j][n=lane&15], D col=lane&15 row=quad*4+reg.
__global__ __launch_bounds__(256) void gemm_scores(const short8* __restrict__ A,
                                                   const short8* __restrict__ B,
                                                   unsigned char* __restrict__ C,
                                                   const float* __restrict__ a_self,
                                                   const float* __restrict__ a_neigh,
                                                   float* __restrict__ es,
                                                   float* __restrict__ en,
                                                   int K8, int M) {
    const int tid = threadIdx.x;
    const int wv = tid >> 6, lane = tid & 63;
    const int q = lane >> 4, t = lane & 15;
    const int m0 = blockIdx.x * 64;
    const int n0 = wv * 64;
    f32x4 acc[4][4];                   // [mr][nc]
#pragma unroll
    for (int mr = 0; mr < 4; mr++)
#pragma unroll
        for (int nc = 0; nc < 4; nc++) acc[mr][nc] = (f32x4){0.f, 0.f, 0.f, 0.f};

    const short8* Ar[4];
#pragma unroll
    for (int mr = 0; mr < 4; mr++) {
        int am = m0 + mr * 16 + t;
        if (am > M - 1) am = M - 1;            // row clamp (stores guarded below)
        Ar[mr] = A + (size_t)am * K8 + q;
    }
    const short8* Bb = B + (size_t)q * 256 + n0 + t;
    for (int kk = 0; kk < K8; kk += 4) {       // 32 k per step
        short8 a0 = Ar[0][kk], a1 = Ar[1][kk], a2 = Ar[2][kk], a3 = Ar[3][kk];
        short8 b0 = Bb[(size_t)kk * 256 + 0];
        short8 b1 = Bb[(size_t)kk * 256 + 16];
        short8 b2 = Bb[(size_t)kk * 256 + 32];
        short8 b3 = Bb[(size_t)kk * 256 + 48];
        acc[0][0] = __builtin_amdgcn_mfma_f32_16x16x32_bf16(a0, b0, acc[0][0], 0, 0, 0);
        acc[0][1] = __builtin_amdgcn_mfma_f32_16x16x32_bf16(a0, b1, acc[0][1], 0, 0, 0);
        acc[0][2] = __builtin_amdgcn_mfma_f32_16x16x32_bf16(a0, b2, acc[0][2], 0, 0, 0);
        acc[0][3] = __builtin_amdgcn_mfma_f32_16x16x32_bf16(a0, b3, acc[0][3], 0, 0, 0);
        acc[1][0] = __builtin_amdgcn_mfma_f32_16x16x32_bf16(a1, b0, acc[1][0], 0, 0, 0);
        acc[1][1] = __builtin_amdgcn_mfma_f32_16x16x32_bf16(a1, b1, acc[1][1], 0, 0, 0);
        acc[1][2] = __builtin_amdgcn_mfma_f32_16x16x32_bf16(a1, b2, acc[1][2], 0, 0, 0);
        acc[1][3] = __builtin_amdgcn_mfma_f32_16x16x32_bf16(a1, b3, acc[1][3], 0, 0, 0);
        acc[2][0] = __builtin_amdgcn_mfma_f32_16x16x32_bf16(a2, b0, acc[2][0], 0, 0, 0);
        acc[2][1] = __builtin_amdgcn_mfma_f32_16x16x32_bf16(a2, b1, acc[2][1], 0, 0, 0);
        acc[2][2] = __builtin_amdgcn_mfma_f32_16x16x32_bf16(a2, b2, acc[2][2], 0, 0, 0);
        acc[2][3] = __builtin_amdgcn_mfma_f32_16x16x32_bf16(a2, b3, acc[2][3], 0, 0, 0);
        acc[3][0] = __builtin_amdgcn_mfma_f32_16x16x32_bf16(a3, b0, acc[3][0], 0, 0, 0);
        acc[3][1] = __builtin_amdgcn_mfma_f32_16x16x32_bf16(a3, b1, acc[3][1], 0, 0, 0);
        acc[3][2] = __builtin_amdgcn_mfma_f32_16x16x32_bf16(a3, b2, acc[3][2], 0, 0, 0);
        acc[3][3] = __builtin_amdgcn_mfma_f32_16x16x32_bf16(a3, b3, acc[3][3], 0, 0, 0);
    }

    // store xp tile (fp8) for the aggregate gather: D row = m0+mr*16+q*4+r, col = n0+nc*16+t
    unsigned char* Cr = C + n0 + t;
#pragma unroll
    for (int mr = 0; mr < 4; mr++) {
#pragma unroll
        for (int r = 0; r < 4; r++) {
            int row = m0 + mr * 16 + q * 4 + r;
            if (row < M) {
                size_t ro = (size_t)row * 256;
                Cr[ro +  0] = f2fp8(acc[mr][0][r]);
                Cr[ro + 16] = f2fp8(acc[mr][1][r]);
                Cr[ro + 32] = f2fp8(acc[mr][2][r]);
                Cr[ro + 48] = f2fp8(acc[mr][3][r]);
            }
        }
    }

    // fused scores: per row, sum D[row][col]*a[col] over this wave's 64 cols
    float as[4], an[4];
#pragma unroll
    for (int nc = 0; nc < 4; nc++) {
        as[nc] = a_self[n0 + nc * 16 + t];
        an[nc] = a_neigh[n0 + nc * 16 + t];
    }
#pragma unroll
    for (int mr = 0; mr < 4; mr++) {
#pragma unroll
        for (int r = 0; r < 4; r++) {
            float pes = acc[mr][0][r] * as[0] + acc[mr][1][r] * as[1]
                      + acc[mr][2][r] * as[2] + acc[mr][3][r] * as[3];
            float pen = acc[mr][0][r] * an[0] + acc[mr][1][r] * an[1]
                      + acc[mr][2][r] * an[2] + acc[mr][3][r] * an[3];
#pragma unroll
            for (int mask = 1; mask < 16; mask <<= 1) {
                pes += __shfl_xor(pes, mask);
                pen += __shfl_xor(pen, mask);
            }
            if (t == 0) {
                int row = m0 + mr * 16 + q * 4 + r;
                if (row < M) {
                    es[(size_t)row * 4 + wv] = pes;
                    en[(size_t)row * 4 + wv] = pen;
                }
            }
        }
    }
}

// ---------- fused softmax + aggregation: one wave per node, quad-per-edge ----------
// Quad q processes edges i = q, q+4, ... ; lane covers 16 channels (one uint4 =
// 16 fp8). Cross-quad shfl_xor(16,32) reduce once per node. mode: partials==
// nullptr -> per-node bf16 rows; else bias+selu + LDS-reduce 4 nodes -> one
// f32 row per block (layer-2: h2 only feeds the sum-pool).
__global__ __launch_bounds__(256) void aggregate(const unsigned char* __restrict__ xp,
                                                 const float* __restrict__ es,
                                                 const float* __restrict__ en,
                                                 const int* __restrict__ cursor,
                                                 const int* __restrict__ ssrc,
                                                 const float* __restrict__ bias,
                                                 ushort* __restrict__ out,
                                                 float* __restrict__ partials, int N) {
    __shared__ float part[4][256];
    int wave = (blockIdx.x * blockDim.x + threadIdx.x) >> 6;
    int wvl = (threadIdx.x >> 6) & 3;
    int lane = threadIdx.x & 63;
    int n = wave;                       // grid exact: wave < N always
    int q = lane >> 4;                  // edge offset within group-of-4
    int t = lane & 15;                  // channel group: channels t*16..+15
    int h = t >> 2;                     // head = (t*16)/64
    int c0 = t * 16;
    int base = n * SLOT_CAP;
    int deg = cursor[n]; deg = (deg > SLOT_CAP) ? SLOT_CAP : deg;
    float esh = es[(size_t)n * 4 + h];
    float acc[16];
#pragma unroll
    for (int j = 0; j < 16; j++) acc[j] = 0.f;
    float dd = 0.f;
    for (int i = q; i < deg; i += 4) {
        int s = ssrc[base + i];
        float ev = __expf(lrelu_f(esh + en[(size_t)s * 4 + h]));
        uint4 u = *(const uint4*)(xp + (size_t)s * 256 + c0);
        dd += ev;
        float f[16];
        fp8x4_decode(u.x, f + 0);
        fp8x4_decode(u.y, f + 4);
        fp8x4_decode(u.z, f + 8);
        fp8x4_decode(u.w, f + 12);
#pragma unroll
        for (int j = 0; j < 16; j++) acc[j] += ev * f[j];
    }
    // cross-quad reduce (masks 16, 32): all quads end with full sums
#pragma unroll
    for (int mask = 16; mask < 64; mask <<= 1) {
        dd += __shfl_xor(dd, mask);
#pragma unroll
        for (int j = 0; j < 16; j++) acc[j] += __shfl_xor(acc[j], mask);
    }
    float inv = (dd > 0.f) ? 1.f / dd : 0.f;
    if (partials == nullptr) {
        if (q == 0) {
            ushort r[16];
#pragma unroll
            for (int j = 0; j < 16; j++)
                r[j] = f2bf(selu_f(acc[j] * inv + bias[c0 + j]));
            uint4* dst = (uint4*)(out + (size_t)n * 256 + c0);
            dst[0] = ((uint4*)r)[0];
            dst[1] = ((uint4*)r)[1];
        }
    } else {
        if (q == 0) {
#pragma unroll
            for (int j = 0; j < 16; j++)
                part[wvl][c0 + j] = selu_f(acc[j] * inv + bias[c0 + j]);
        }
        __syncthreads();
        if (wvl == 0 && q == 0) {
#pragma unroll
            for (int jj = 0; jj < 4; jj++) {
                int c = c0 + jj * 4;
                float4 s;
                s.x = part[0][c + 0] + part[1][c + 0] + part[2][c + 0] + part[3][c + 0];
                s.y = part[0][c + 1] + part[1][c + 1] + part[2][c + 1] + part[3][c + 1];
                s.z = part[0][c + 2] + part[1][c + 2] + part[2][c + 2] + part[3][c + 2];
                s.w = part[0][c + 3] + part[1][c + 3] + part[2][c + 3] + part[3][c + 3];
                *(float4*)(partials + (size_t)blockIdx.x * 256 + c) = s;
            }
        }
    }
}

// ---------- reduce per-block partials [R][256] -> g[256] ----------
__global__ __launch_bounds__(256) void colsum_part(const float* __restrict__ p,
                                                   float* __restrict__ g, int R) {
    __shared__ float part[4][256];
    int tid = threadIdx.x;
    int rg = tid >> 6;            // row group 0..3
    int c0 = (tid & 63) * 4;      // channel group
    float4 acc = {0.f, 0.f, 0.f, 0.f};
    for (int r = blockIdx.x * 4 + rg; r < R; r += gridDim.x * 4) {
        float4 v = *(const float4*)(p + (size_t)r * 256 + c0);
        acc.x += v.x; acc.y += v.y; acc.z += v.z; acc.w += v.w;
    }
    *(float4*)(&part[rg][c0]) = acc;
    __syncthreads();
    if (rg == 0) {
        float4 s = acc;
        for (int r = 1; r < 4; r++) {
            s.x += part[r][c0 + 0]; s.y += part[r][c0 + 1];
            s.z += part[r][c0 + 2]; s.w += part[r][c0 + 3];
        }
        atomicAdd(&g[c0 + 0], s.x);
        atomicAdd(&g[c0 + 1], s.y);
        atomicAdd(&g[c0 + 2], s.z);
        atomicAdd(&g[c0 + 3], s.w);
    }
}

// ---------- MLP head, single block ----------
__global__ __launch_bounds__(256) void mlp_head(const float* __restrict__ g,
                                                const float* __restrict__ Wd1, const float* __restrict__ bd1,
                                                const float* __restrict__ Wd2, const float* __restrict__ bd2,
                                                const float* __restrict__ Wo, const float* __restrict__ bo,
                                                float* __restrict__ out) {
    __shared__ float sg[256], y1[64], y2[32];
    int t = threadIdx.x;
    sg[t] = g[t];
    __syncthreads();
    if (t < 64) {
        float s = bd1[t];
        for (int k = 0; k < 256; k++) s += sg[k] * Wd1[k * 64 + t];
        y1[t] = selu_f(s);
    }
    __syncthreads();
    if (t < 32) {
        float s = bd2[t];
        for (int k = 0; k < 64; k++) s += y1[k] * Wd2[k * 32 + t];
        y2[t] = selu_f(s);
    }
    __syncthreads();
    if (t == 0) {
        float s = bo[0];
        for (int k = 0; k < 32; k++) s += y2[k] * Wo[k];
        out[0] = s;
    }
}

// ---------- host launcher ----------
extern "C" void kernel_launch(void* const* d_in, const int* in_sizes, int n_in,
                              void* d_out, int out_size, void* d_ws, size_t ws_size,
                              hipStream_t stream) {
    const float* x   = (const float*)d_in[0];
    const int*   ei  = (const int*)d_in[1];
    const float* W1  = (const float*)d_in[2];
    const float* as1 = (const float*)d_in[3];
    const float* an1 = (const float*)d_in[4];
    const float* b1  = (const float*)d_in[5];
    const float* W2  = (const float*)d_in[6];
    const float* as2 = (const float*)d_in[7];
    const float* an2 = (const float*)d_in[8];
    const float* b2  = (const float*)d_in[9];
    const float* Wd1 = (const float*)d_in[10];
    const float* bd1 = (const float*)d_in[11];
    const float* Wd2 = (const float*)d_in[12];
    const float* bd2 = (const float*)d_in[13];
    const float* Wo  = (const float*)d_in[14];
    const float* bo  = (const float*)d_in[15];
    const int* tgt  = ei;
    const int* srcp = ei + N_EDGES;

    char* w = (char*)d_ws;
    size_t off_b = 0;
    auto alloc = [&](size_t bytes) -> void* {
        void* p = w + off_b;
        off_b = (off_b + bytes + 255) & ~(size_t)255;
        return p;
    };
    ushort* Apx  = (ushort*)alloc((size_t)N_NODES * 128 * 2);       // x in bf16
    ushort* Bp1  = (ushort*)alloc((size_t)128 * 256 * 2);           // W1 packed
    ushort* Bp2  = (ushort*)alloc((size_t)256 * 256 * 2);           // W2 packed
    unsigned char* xp8 = (unsigned char*)alloc((size_t)N_NODES * 256); // projection, fp8
    ushort* h1b  = (ushort*)alloc((size_t)N_NODES * 256 * 2);       // h1 (bf16)
    float* es    = (float*)alloc((size_t)N_NODES * 4 * 4);
    float* en    = (float*)alloc((size_t)N_NODES * 4 * 4);
    int*   cursor= (int*)alloc((size_t)N_NODES * 4);
    int*   ssrc  = (int*)alloc((size_t)N_NODES * SLOT_CAP * 4);     // slot-CSR (19.2 MB)
    float* pp    = (float*)alloc((size_t)AGG_BLOCKS * 256 * 4);     // layer-2 block partials
    float* g     = (float*)alloc(1024);

    const int EB = (N_EDGES + 255) / 256;
    const int GB = (N_NODES + 63) / 64;    // 782 gemm blocks

    // ===== pack + init (1 launch) =====
    pack_all<<<(N_NODES * 128 / 8 + 255) / 256, 256, 0, stream>>>(
        x, Apx, W1, Bp1, W2, Bp2, cursor, g);

    // ===== slot-CSR build (1 launch) =====
    edge_scatter<<<EB, 256, 0, stream>>>(tgt, srcp, cursor, ssrc, N_EDGES);

    // ===== layer 1 =====
    gemm_scores<<<GB, 256, 0, stream>>>((const short8*)Apx, (const short8*)Bp1,
                                        xp8, as1, an1, es, en, 16, N_NODES);
    aggregate<<<AGG_BLOCKS, 256, 0, stream>>>(xp8, es, en, cursor, ssrc, b1, h1b, nullptr, N_NODES);

    // ===== layer 2 =====
    gemm_scores<<<GB, 256, 0, stream>>>((const short8*)h1b, (const short8*)Bp2,
                                        xp8, as2, an2, es, en, 32, N_NODES);
    aggregate<<<AGG_BLOCKS, 256, 0, stream>>>(xp8, es, en, cursor, ssrc, b2, nullptr, pp, N_NODES);

    // ===== pool + MLP =====
    colsum_part<<<128, 256, 0, stream>>>(pp, g, AGG_BLOCKS);
    mlp_head<<<1, 256, 0, stream>>>(g, Wd1, bd1, Wd2, bd2, Wo, bo, (float*)d_out);
}

// Round 11
// 345.877 us; speedup vs baseline: 1.0677x; 1.0677x over previous
//
#include <hip/hip_runtime.h>
#include <hip/hip_bf16.h>
#include <hip/hip_fp8.h>
#include <math.h>

#define N_NODES 50000
#define N_EDGES 800000
#define SLOT_CAP 96                     // max in-degree slots per node (E[deg]=16, max<~50)
#define AGG_BLOCKS (N_NODES / 4)        // 12500 aggregate blocks (4 nodes each)

typedef __attribute__((ext_vector_type(8))) short short8;   // 8 x bf16 (4 VGPRs)
typedef __attribute__((ext_vector_type(4))) float f32x4;    // MFMA accumulator
typedef __attribute__((ext_vector_type(2))) float f32x2;

// ---------- device helpers ----------
__device__ __forceinline__ float selu_f(float x) {
    const float scale = 1.0507009873554805f;
    const float alpha = 1.6732632423543772f;
    return x > 0.f ? scale * x : scale * alpha * (expf(x) - 1.f);
}
__device__ __forceinline__ float lrelu_f(float x) {
    return x >= 0.f ? x : 0.2f * x;
}
__device__ __forceinline__ ushort f2bf(float f) {
    __hip_bfloat16 h = __float2bfloat16(f);   // RNE
    return *(ushort*)&h;
}
__device__ __forceinline__ unsigned char f2fp8(float f) {
    __hip_fp8_e4m3 q(f);                       // OCP e4m3, RNE+sat (software fallback)
    return (unsigned char)q.__x;
}
__device__ __forceinline__ float fp82f(unsigned char b) {
    __hip_fp8_e4m3 q; q.__x = (__hip_fp8_storage_t)b;
    return (float)q;
}
// decode 4 packed fp8 (one dword) -> 4 floats
__device__ __forceinline__ void fp8x4_decode(unsigned u, float* o) {
#if __has_builtin(__builtin_amdgcn_cvt_pk_f32_fp8)
    f32x2 lo = __builtin_amdgcn_cvt_pk_f32_fp8((int)u, false);
    f32x2 hi = __builtin_amdgcn_cvt_pk_f32_fp8((int)u, true);
    o[0] = lo.x; o[1] = lo.y; o[2] = hi.x; o[3] = hi.y;
#else
    o[0] = fp82f(u & 0xff);
    o[1] = fp82f((u >> 8) & 0xff);
    o[2] = fp82f((u >> 16) & 0xff);
    o[3] = fp82f(u >> 24);
#endif
}
// encode 4 floats -> packed fp8 dword (HW v_cvt_pk_fp8_f32: 2 insts)
__device__ __forceinline__ unsigned fp8x4_encode(float f0, float f1, float f2, float f3) {
#if __has_builtin(__builtin_amdgcn_cvt_pk_fp8_f32)
    int v = 0;
    v = __builtin_amdgcn_cvt_pk_fp8_f32(f0, f1, v, false);
    v = __builtin_amdgcn_cvt_pk_fp8_f32(f2, f3, v, true);
    return (unsigned)v;
#else
    return (unsigned)f2fp8(f0) | ((unsigned)f2fp8(f1) << 8) |
           ((unsigned)f2fp8(f2) << 16) | ((unsigned)f2fp8(f3) << 24);
#endif
}

// ---------- fused pack + init (once per call) ----------
__global__ void pack_all(const float* __restrict__ x, ushort* __restrict__ Apx,
                         const float* __restrict__ W1, ushort* __restrict__ Bp1,
                         const float* __restrict__ W2, ushort* __restrict__ Bp2,
                         int* __restrict__ cursor, float* __restrict__ g) {
    int i = blockIdx.x * blockDim.x + threadIdx.x;
    if (i < N_NODES * 128 / 8) {
        const float4* p = (const float4*)x + (size_t)i * 2;
        float4 a = p[0], b = p[1];
        ushort u[8] = { f2bf(a.x), f2bf(a.y), f2bf(a.z), f2bf(a.w),
                        f2bf(b.x), f2bf(b.y), f2bf(b.z), f2bf(b.w) };
        *(uint4*)(Apx + (size_t)i * 8) = *(uint4*)u;
    }
    if (i < 16 * 256) {                     // W1: K8 = 16
        int kg = i >> 8, n = i & 255;
        ushort u[8];
#pragma unroll
        for (int j = 0; j < 8; j++) u[j] = f2bf(W1[(size_t)(kg * 8 + j) * 256 + n]);
        *(uint4*)(Bp1 + ((size_t)kg * 256 + n) * 8) = *(uint4*)u;
    }
    if (i < 32 * 256) {                     // W2: K8 = 32
        int kg = i >> 8, n = i & 255;
        ushort u[8];
#pragma unroll
        for (int j = 0; j < 8; j++) u[j] = f2bf(W2[(size_t)(kg * 8 + j) * 256 + n]);
        *(uint4*)(Bp2 + ((size_t)kg * 256 + n) * 8) = *(uint4*)u;
    }
    if (i < N_NODES) cursor[i] = 0;
    if (i < 256) g[i] = 0.f;
}

// ---------- slot-CSR build: single pass (hist+scan+scatter collapsed) ----------
__global__ void edge_scatter(const int* __restrict__ tgt, const int* __restrict__ src,
                             int* __restrict__ cursor, int* __restrict__ ssrc, int E) {
    int e = blockIdx.x * blockDim.x + threadIdx.x;
    if (e >= E) return;
    int t = tgt[e];
    int r = atomicAdd(&cursor[t], 1);
    if (r < SLOT_CAP) ssrc[(size_t)t * SLOT_CAP + r] = src[e];
}

// ---------- MFMA GEMM (64-row block, 4x4 acc/wave) + fused scores ----------
// block = 256 thr = 4 waves; block tile 64 rows x 256 cols; wave wv owns all 64
// rows x cols wv*64..+63 == head wv. 16 MFMA : 8 loads per 32-k step.
// fp8 epilogue uses HW cvt_pk_fp8_f32 (R10 post-mortem: software encode was
// ~1000 VALU insts/lane and dominated the kernel).
// Fragment layouts (guide §3, m89/m91-verified): A[m=lane&15][k=quad*8+j],
// B[k=quad*8+j][n=lane&15], D col=lane&15 row=quad*4+reg.
__global__ __launch_bounds__(256) void gemm_scores(const short8* __restrict__ A,
                                                   const short8* __restrict__ B,
                                                   unsigned char* __restrict__ C,
                                                   const float* __restrict__ a_self,
                                                   const float* __restrict__ a_neigh,
                                                   float* __restrict__ es,
                                                   float* __restrict__ en,
                                                   int K8, int M) {
    const int tid = threadIdx.x;
    const int wv = tid >> 6, lane = tid & 63;
    const int q = lane >> 4, t = lane & 15;
    const int m0 = blockIdx.x * 64;
    const int n0 = wv * 64;
    f32x4 acc[4][4];                   // [mr][nc]
#pragma unroll
    for (int mr = 0; mr < 4; mr++)
#pragma unroll
        for (int nc = 0; nc < 4; nc++) acc[mr][nc] = (f32x4){0.f, 0.f, 0.f, 0.f};

    const short8* Ar[4];
#pragma unroll
    for (int mr = 0; mr < 4; mr++) {
        int am = m0 + mr * 16 + t;
        if (am > M - 1) am = M - 1;            // row clamp (stores guarded below)
        Ar[mr] = A + (size_t)am * K8 + q;
    }
    const short8* Bb = B + (size_t)q * 256 + n0 + t;
    for (int kk = 0; kk < K8; kk += 4) {       // 32 k per step
        short8 a0 = Ar[0][kk], a1 = Ar[1][kk], a2 = Ar[2][kk], a3 = Ar[3][kk];
        short8 b0 = Bb[(size_t)kk * 256 + 0];
        short8 b1 = Bb[(size_t)kk * 256 + 16];
        short8 b2 = Bb[(size_t)kk * 256 + 32];
        short8 b3 = Bb[(size_t)kk * 256 + 48];
        acc[0][0] = __builtin_amdgcn_mfma_f32_16x16x32_bf16(a0, b0, acc[0][0], 0, 0, 0);
        acc[0][1] = __builtin_amdgcn_mfma_f32_16x16x32_bf16(a0, b1, acc[0][1], 0, 0, 0);
        acc[0][2] = __builtin_amdgcn_mfma_f32_16x16x32_bf16(a0, b2, acc[0][2], 0, 0, 0);
        acc[0][3] = __builtin_amdgcn_mfma_f32_16x16x32_bf16(a0, b3, acc[0][3], 0, 0, 0);
        acc[1][0] = __builtin_amdgcn_mfma_f32_16x16x32_bf16(a1, b0, acc[1][0], 0, 0, 0);
        acc[1][1] = __builtin_amdgcn_mfma_f32_16x16x32_bf16(a1, b1, acc[1][1], 0, 0, 0);
        acc[1][2] = __builtin_amdgcn_mfma_f32_16x16x32_bf16(a1, b2, acc[1][2], 0, 0, 0);
        acc[1][3] = __builtin_amdgcn_mfma_f32_16x16x32_bf16(a1, b3, acc[1][3], 0, 0, 0);
        acc[2][0] = __builtin_amdgcn_mfma_f32_16x16x32_bf16(a2, b0, acc[2][0], 0, 0, 0);
        acc[2][1] = __builtin_amdgcn_mfma_f32_16x16x32_bf16(a2, b1, acc[2][1], 0, 0, 0);
        acc[2][2] = __builtin_amdgcn_mfma_f32_16x16x32_bf16(a2, b2, acc[2][2], 0, 0, 0);
        acc[2][3] = __builtin_amdgcn_mfma_f32_16x16x32_bf16(a2, b3, acc[2][3], 0, 0, 0);
        acc[3][0] = __builtin_amdgcn_mfma_f32_16x16x32_bf16(a3, b0, acc[3][0], 0, 0, 0);
        acc[3][1] = __builtin_amdgcn_mfma_f32_16x16x32_bf16(a3, b1, acc[3][1], 0, 0, 0);
        acc[3][2] = __builtin_amdgcn_mfma_f32_16x16x32_bf16(a3, b2, acc[3][2], 0, 0, 0);
        acc[3][3] = __builtin_amdgcn_mfma_f32_16x16x32_bf16(a3, b3, acc[3][3], 0, 0, 0);
    }

    // store xp tile (fp8, HW packed encode): D row = m0+mr*16+q*4+r, col = n0+nc*16+t
    unsigned char* Cr = C + n0 + t;
#pragma unroll
    for (int mr = 0; mr < 4; mr++) {
#pragma unroll
        for (int r = 0; r < 4; r++) {
            int row = m0 + mr * 16 + q * 4 + r;
            if (row < M) {
                size_t ro = (size_t)row * 256;
                unsigned pk = fp8x4_encode(acc[mr][0][r], acc[mr][1][r],
                                           acc[mr][2][r], acc[mr][3][r]);
                Cr[ro +  0] = (unsigned char)(pk & 0xff);
                Cr[ro + 16] = (unsigned char)((pk >> 8) & 0xff);
                Cr[ro + 32] = (unsigned char)((pk >> 16) & 0xff);
                Cr[ro + 48] = (unsigned char)(pk >> 24);
            }
        }
    }

    // fused scores: per row, sum D[row][col]*a[col] over this wave's 64 cols
    float as[4], an[4];
#pragma unroll
    for (int nc = 0; nc < 4; nc++) {
        as[nc] = a_self[n0 + nc * 16 + t];
        an[nc] = a_neigh[n0 + nc * 16 + t];
    }
#pragma unroll
    for (int mr = 0; mr < 4; mr++) {
#pragma unroll
        for (int r = 0; r < 4; r++) {
            float pes = acc[mr][0][r] * as[0] + acc[mr][1][r] * as[1]
                      + acc[mr][2][r] * as[2] + acc[mr][3][r] * as[3];
            float pen = acc[mr][0][r] * an[0] + acc[mr][1][r] * an[1]
                      + acc[mr][2][r] * an[2] + acc[mr][3][r] * an[3];
#pragma unroll
            for (int mask = 1; mask < 16; mask <<= 1) {
                pes += __shfl_xor(pes, mask);
                pen += __shfl_xor(pen, mask);
            }
            if (t == 0) {
                int row = m0 + mr * 16 + q * 4 + r;
                if (row < M) {
                    es[(size_t)row * 4 + wv] = pes;
                    en[(size_t)row * 4 + wv] = pen;
                }
            }
        }
    }
}

// ---------- fused softmax + aggregation: one wave per node (R9-verified) ----------
// mode: partials==nullptr -> write per-node bf16 rows to out;
//       else -> apply bias+selu, LDS-reduce the block's 4 nodes, write one
//       f32 row per block to partials (layer-2: h2 only feeds the sum-pool).
__global__ __launch_bounds__(256) void aggregate(const unsigned char* __restrict__ xp,
                                                 const float* __restrict__ es,
                                                 const float* __restrict__ en,
                                                 const int* __restrict__ cursor,
                                                 const int* __restrict__ ssrc,
                                                 const float* __restrict__ bias,
                                                 ushort* __restrict__ out,
                                                 float* __restrict__ partials, int N) {
    __shared__ float part[4][256];
    int wave = (blockIdx.x * blockDim.x + threadIdx.x) >> 6;
    int wv = (threadIdx.x >> 6) & 3;
    int lane = threadIdx.x & 63;
    if (wave >= N) return;                  // grid exact: never taken
    int n = wave;
    int e0 = n * SLOT_CAP;
    int deg = cursor[n]; deg = (deg > SLOT_CAP) ? SLOT_CAP : deg;
    int e1 = e0 + deg;
    int h = lane >> 4;                 // lane's head (channels lane*4..lane*4+3)
    int c0 = lane * 4;
    float esh = es[(size_t)n * 4 + h];
    float dd = 0.f;
    float a0 = 0.f, a1 = 0.f, a2 = 0.f, a3 = 0.f;
    float b0 = 0.f, b1 = 0.f, b2 = 0.f, b3 = 0.f;
    int e = e0;
    for (; e + 1 < e1; e += 2) {
        int sA = __builtin_amdgcn_readfirstlane(ssrc[e]);
        int sB = __builtin_amdgcn_readfirstlane(ssrc[e + 1]);
        float evA = __expf(lrelu_f(esh + en[(size_t)sA * 4 + h]));
        float evB = __expf(lrelu_f(esh + en[(size_t)sB * 4 + h]));
        unsigned uA = *(const unsigned*)(xp + (size_t)sA * 256 + c0);
        unsigned uB = *(const unsigned*)(xp + (size_t)sB * 256 + c0);
        dd += evA + evB;
        float fA[4], fB[4];
        fp8x4_decode(uA, fA);
        fp8x4_decode(uB, fB);
        a0 += evA * fA[0]; a1 += evA * fA[1]; a2 += evA * fA[2]; a3 += evA * fA[3];
        b0 += evB * fB[0]; b1 += evB * fB[1]; b2 += evB * fB[2]; b3 += evB * fB[3];
    }
    if (e < e1) {
        int s = __builtin_amdgcn_readfirstlane(ssrc[e]);
        float ev = __expf(lrelu_f(esh + en[(size_t)s * 4 + h]));
        unsigned u = *(const unsigned*)(xp + (size_t)s * 256 + c0);
        dd += ev;
        float f[4];
        fp8x4_decode(u, f);
        a0 += ev * f[0]; a1 += ev * f[1]; a2 += ev * f[2]; a3 += ev * f[3];
    }
    float inv = (dd > 0.f) ? 1.f / dd : 0.f;
    float4 bb = *(const float4*)(bias + c0);
    float r0 = selu_f((a0 + b0) * inv + bb.x);
    float r1 = selu_f((a1 + b1) * inv + bb.y);
    float r2 = selu_f((a2 + b2) * inv + bb.z);
    float r3 = selu_f((a3 + b3) * inv + bb.w);
    if (partials == nullptr) {
        ushort r[4] = { f2bf(r0), f2bf(r1), f2bf(r2), f2bf(r3) };
        *(uint2*)(out + (size_t)n * 256 + c0) = *(uint2*)r;
    } else {
        part[wv][c0 + 0] = r0; part[wv][c0 + 1] = r1;
        part[wv][c0 + 2] = r2; part[wv][c0 + 3] = r3;
        __syncthreads();
        if (wv == 0) {
            float4 s;
            s.x = r0 + part[1][c0 + 0] + part[2][c0 + 0] + part[3][c0 + 0];
            s.y = r1 + part[1][c0 + 1] + part[2][c0 + 1] + part[3][c0 + 1];
            s.z = r2 + part[1][c0 + 2] + part[2][c0 + 2] + part[3][c0 + 2];
            s.w = r3 + part[1][c0 + 3] + part[2][c0 + 3] + part[3][c0 + 3];
            *(float4*)(partials + (size_t)blockIdx.x * 256 + c0) = s;
        }
    }
}

// ---------- reduce per-block partials [R][256] -> g[256] ----------
__global__ __launch_bounds__(256) void colsum_part(const float* __restrict__ p,
                                                   float* __restrict__ g, int R) {
    __shared__ float part[4][256];
    int tid = threadIdx.x;
    int rg = tid >> 6;            // row group 0..3
    int c0 = (tid & 63) * 4;      // channel group
    float4 acc = {0.f, 0.f, 0.f, 0.f};
    for (int r = blockIdx.x * 4 + rg; r < R; r += gridDim.x * 4) {
        float4 v = *(const float4*)(p + (size_t)r * 256 + c0);
        acc.x += v.x; acc.y += v.y; acc.z += v.z; acc.w += v.w;
    }
    *(float4*)(&part[rg][c0]) = acc;
    __syncthreads();
    if (rg == 0) {
        float4 s = acc;
        for (int r = 1; r < 4; r++) {
            s.x += part[r][c0 + 0]; s.y += part[r][c0 + 1];
            s.z += part[r][c0 + 2]; s.w += part[r][c0 + 3];
        }
        atomicAdd(&g[c0 + 0], s.x);
        atomicAdd(&g[c0 + 1], s.y);
        atomicAdd(&g[c0 + 2], s.z);
        atomicAdd(&g[c0 + 3], s.w);
    }
}

// ---------- MLP head, single block ----------
__global__ __launch_bounds__(256) void mlp_head(const float* __restrict__ g,
                                                const float* __restrict__ Wd1, const float* __restrict__ bd1,
                                                const float* __restrict__ Wd2, const float* __restrict__ bd2,
                                                const float* __restrict__ Wo, const float* __restrict__ bo,
                                                float* __restrict__ out) {
    __shared__ float sg[256], y1[64], y2[32];
    int t = threadIdx.x;
    sg[t] = g[t];
    __syncthreads();
    if (t < 64) {
        float s = bd1[t];
        for (int k = 0; k < 256; k++) s += sg[k] * Wd1[k * 64 + t];
        y1[t] = selu_f(s);
    }
    __syncthreads();
    if (t < 32) {
        float s = bd2[t];
        for (int k = 0; k < 64; k++) s += y1[k] * Wd2[k * 32 + t];
        y2[t] = selu_f(s);
    }
    __syncthreads();
    if (t == 0) {
        float s = bo[0];
        for (int k = 0; k < 32; k++) s += y2[k] * Wo[k];
        out[0] = s;
    }
}

// ---------- host launcher ----------
extern "C" void kernel_launch(void* const* d_in, const int* in_sizes, int n_in,
                              void* d_out, int out_size, void* d_ws, size_t ws_size,
                              hipStream_t stream) {
    const float* x   = (const float*)d_in[0];
    const int*   ei  = (const int*)d_in[1];
    const float* W1  = (const float*)d_in[2];
    const float* as1 = (const float*)d_in[3];
    const float* an1 = (const float*)d_in[4];
    const float* b1  = (const float*)d_in[5];
    const float* W2  = (const float*)d_in[6];
    const float* as2 = (const float*)d_in[7];
    const float* an2 = (const float*)d_in[8];
    const float* b2  = (const float*)d_in[9];
    const float* Wd1 = (const float*)d_in[10];
    const float* bd1 = (const float*)d_in[11];
    const float* Wd2 = (const float*)d_in[12];
    const float* bd2 = (const float*)d_in[13];
    const float* Wo  = (const float*)d_in[14];
    const float* bo  = (const float*)d_in[15];
    const int* tgt  = ei;
    const int* srcp = ei + N_EDGES;

    char* w = (char*)d_ws;
    size_t off_b = 0;
    auto alloc = [&](size_t bytes) -> void* {
        void* p = w + off_b;
        off_b = (off_b + bytes + 255) & ~(size_t)255;
        return p;
    };
    ushort* Apx  = (ushort*)alloc((size_t)N_NODES * 128 * 2);       // x in bf16
    ushort* Bp1  = (ushort*)alloc((size_t)128 * 256 * 2);           // W1 packed
    ushort* Bp2  = (ushort*)alloc((size_t)256 * 256 * 2);           // W2 packed
    unsigned char* xp8 = (unsigned char*)alloc((size_t)N_NODES * 256); // projection, fp8
    ushort* h1b  = (ushort*)alloc((size_t)N_NODES * 256 * 2);       // h1 (bf16)
    float* es    = (float*)alloc((size_t)N_NODES * 4 * 4);
    float* en    = (float*)alloc((size_t)N_NODES * 4 * 4);
    int*   cursor= (int*)alloc((size_t)N_NODES * 4);
    int*   ssrc  = (int*)alloc((size_t)N_NODES * SLOT_CAP * 4);     // slot-CSR (19.2 MB)
    float* pp    = (float*)alloc((size_t)AGG_BLOCKS * 256 * 4);     // layer-2 block partials
    float* g     = (float*)alloc(1024);

    const int EB = (N_EDGES + 255) / 256;
    const int GB = (N_NODES + 63) / 64;    // 782 gemm blocks

    // ===== pack + init (1 launch) =====
    pack_all<<<(N_NODES * 128 / 8 + 255) / 256, 256, 0, stream>>>(
        x, Apx, W1, Bp1, W2, Bp2, cursor, g);

    // ===== slot-CSR build (1 launch) =====
    edge_scatter<<<EB, 256, 0, stream>>>(tgt, srcp, cursor, ssrc, N_EDGES);

    // ===== layer 1 =====
    gemm_scores<<<GB, 256, 0, stream>>>((const short8*)Apx, (const short8*)Bp1,
                                        xp8, as1, an1, es, en, 16, N_NODES);
    aggregate<<<AGG_BLOCKS, 256, 0, stream>>>(xp8, es, en, cursor, ssrc, b1, h1b, nullptr, N_NODES);

    // ===== layer 2 =====
    gemm_scores<<<GB, 256, 0, stream>>>((const short8*)h1b, (const short8*)Bp2,
                                        xp8, as2, an2, es, en, 32, N_NODES);
    aggregate<<<AGG_BLOCKS, 256, 0, stream>>>(xp8, es, en, cursor, ssrc, b2, nullptr, pp, N_NODES);

    // ===== pool + MLP =====
    colsum_part<<<128, 256, 0, stream>>>(pp, g, AGG_BLOCKS);
    mlp_head<<<1, 256, 0, stream>>>(g, Wd1, bd1, Wd2, bd2, Wo, bo, (float*)d_out);
}

// Round 12
// 338.097 us; speedup vs baseline: 1.0922x; 1.0230x over previous
//
#include <hip/hip_runtime.h>
#include <hip/hip_bf16.h>
#include <hip/hip_fp8.h>
#include <math.h>

#define N_NODES 50000
#define N_EDGES 800000
#define SLOT_CAP 96                     // max in-degree slots per node (E[deg]=16, max<~50)
#define AGG_BLOCKS (N_NODES / 4)        // 12500 aggregate blocks (4 nodes each)

typedef __attribute__((ext_vector_type(8))) short short8;   // 8 x bf16 (4 VGPRs)
typedef __attribute__((ext_vector_type(4))) float f32x4;    // MFMA accumulator
typedef __attribute__((ext_vector_type(2))) float f32x2;

// ---------- device helpers ----------
__device__ __forceinline__ float selu_f(float x) {
    const float scale = 1.0507009873554805f;
    const float alpha = 1.6732632423543772f;
    return x > 0.f ? scale * x : scale * alpha * (expf(x) - 1.f);
}
__device__ __forceinline__ float lrelu_f(float x) {
    return x >= 0.f ? x : 0.2f * x;
}
__device__ __forceinline__ ushort f2bf(float f) {
    __hip_bfloat16 h = __float2bfloat16(f);   // RNE
    return *(ushort*)&h;
}
__device__ __forceinline__ unsigned char f2fp8(float f) {
    __hip_fp8_e4m3 q(f);                       // OCP e4m3, RNE+sat (software fallback)
    return (unsigned char)q.__x;
}
__device__ __forceinline__ float fp82f(unsigned char b) {
    __hip_fp8_e4m3 q; q.__x = (__hip_fp8_storage_t)b;
    return (float)q;
}
// decode 4 packed fp8 (one dword) -> 4 floats
__device__ __forceinline__ void fp8x4_decode(unsigned u, float* o) {
#if __has_builtin(__builtin_amdgcn_cvt_pk_f32_fp8)
    f32x2 lo = __builtin_amdgcn_cvt_pk_f32_fp8((int)u, false);
    f32x2 hi = __builtin_amdgcn_cvt_pk_f32_fp8((int)u, true);
    o[0] = lo.x; o[1] = lo.y; o[2] = hi.x; o[3] = hi.y;
#else
    o[0] = fp82f(u & 0xff);
    o[1] = fp82f((u >> 8) & 0xff);
    o[2] = fp82f((u >> 16) & 0xff);
    o[3] = fp82f(u >> 24);
#endif
}
// encode 4 floats -> packed fp8 dword (HW v_cvt_pk_fp8_f32)
__device__ __forceinline__ unsigned fp8x4_encode(float f0, float f1, float f2, float f3) {
#if __has_builtin(__builtin_amdgcn_cvt_pk_fp8_f32)
    int v = 0;
    v = __builtin_amdgcn_cvt_pk_fp8_f32(f0, f1, v, false);
    v = __builtin_amdgcn_cvt_pk_fp8_f32(f2, f3, v, true);
    return (unsigned)v;
#else
    return (unsigned)f2fp8(f0) | ((unsigned)f2fp8(f1) << 8) |
           ((unsigned)f2fp8(f2) << 16) | ((unsigned)f2fp8(f3) << 24);
#endif
}

// ---------- fused pack + init (once per call) ----------
__global__ void pack_all(const float* __restrict__ x, ushort* __restrict__ Apx,
                         const float* __restrict__ W1, ushort* __restrict__ Bp1,
                         const float* __restrict__ W2, ushort* __restrict__ Bp2,
                         int* __restrict__ cursor, float* __restrict__ g) {
    int i = blockIdx.x * blockDim.x + threadIdx.x;
    if (i < N_NODES * 128 / 8) {
        const float4* p = (const float4*)x + (size_t)i * 2;
        float4 a = p[0], b = p[1];
        ushort u[8] = { f2bf(a.x), f2bf(a.y), f2bf(a.z), f2bf(a.w),
                        f2bf(b.x), f2bf(b.y), f2bf(b.z), f2bf(b.w) };
        *(uint4*)(Apx + (size_t)i * 8) = *(uint4*)u;
    }
    if (i < 16 * 256) {                     // W1: K8 = 16
        int kg = i >> 8, n = i & 255;
        ushort u[8];
#pragma unroll
        for (int j = 0; j < 8; j++) u[j] = f2bf(W1[(size_t)(kg * 8 + j) * 256 + n]);
        *(uint4*)(Bp1 + ((size_t)kg * 256 + n) * 8) = *(uint4*)u;
    }
    if (i < 32 * 256) {                     // W2: K8 = 32
        int kg = i >> 8, n = i & 255;
        ushort u[8];
#pragma unroll
        for (int j = 0; j < 8; j++) u[j] = f2bf(W2[(size_t)(kg * 8 + j) * 256 + n]);
        *(uint4*)(Bp2 + ((size_t)kg * 256 + n) * 8) = *(uint4*)u;
    }
    if (i < N_NODES) cursor[i] = 0;
    if (i < 256) g[i] = 0.f;
}

// ---------- slot-CSR build: single pass (hist+scan+scatter collapsed) ----------
__global__ void edge_scatter(const int* __restrict__ tgt, const int* __restrict__ src,
                             int* __restrict__ cursor, int* __restrict__ ssrc, int E) {
    int e = blockIdx.x * blockDim.x + threadIdx.x;
    if (e >= E) return;
    int t = tgt[e];
    int r = atomicAdd(&cursor[t], 1);
    if (r < SLOT_CAP) ssrc[(size_t)t * SLOT_CAP + r] = src[e];
}

// ---------- MFMA GEMM (64-row block, LDS-staged A) + fused scores ----------
// block = 256 thr = 4 waves; block tile 64 rows x 256 cols; wave wv owns all 64
// rows x cols wv*64..+63 == head wv. A-slice (64 rows x 64B) staged in LDS per
// 32-k step: coalesced 16-line/wave loads, loaded ONCE per block (R11's direct
// loads were 64-line gathers x4 wave redundancy — the suspected ~60 us cost).
// LDS row stride 80B -> 2-way bank aliasing only (free, m136).
// Fragment layouts (guide §3, m89/m91-verified): A[m=lane&15][k=quad*8+j],
// B[k=quad*8+j][n=lane&15], D col=lane&15 row=quad*4+reg.
__global__ __launch_bounds__(256) void gemm_scores(const short8* __restrict__ A,
                                                   const short8* __restrict__ B,
                                                   unsigned char* __restrict__ C,
                                                   const float* __restrict__ a_self,
                                                   const float* __restrict__ a_neigh,
                                                   float* __restrict__ es,
                                                   float* __restrict__ en,
                                                   int K8, int M) {
    __shared__ short8 Atile[64][5];        // [row][chunk 0..3], +1 pad (80B row stride)
    const int tid = threadIdx.x;
    const int wv = tid >> 6, lane = tid & 63;
    const int q = lane >> 4, t = lane & 15;
    const int m0 = blockIdx.x * 64;
    const int n0 = wv * 64;

    // staging assignment: thread -> (row, chunk)
    const int srow = tid >> 2, sc = tid & 3;
    int grow = m0 + srow; if (grow > M - 1) grow = M - 1;   // row clamp (stores guarded)
    const short8* Ag = A + (size_t)grow * K8 + sc;

    f32x4 acc[4][4];                   // [mr][nc]
#pragma unroll
    for (int mr = 0; mr < 4; mr++)
#pragma unroll
        for (int nc = 0; nc < 4; nc++) acc[mr][nc] = (f32x4){0.f, 0.f, 0.f, 0.f};

    const short8* Bb = B + (size_t)q * 256 + n0 + t;
    for (int kk = 0; kk < K8; kk += 4) {       // 32 k per step
        __syncthreads();
        Atile[srow][sc] = Ag[kk];
        __syncthreads();
        short8 a0 = Atile[t][q];
        short8 a1 = Atile[16 + t][q];
        short8 a2 = Atile[32 + t][q];
        short8 a3 = Atile[48 + t][q];
        short8 b0 = Bb[(size_t)kk * 256 + 0];
        short8 b1 = Bb[(size_t)kk * 256 + 16];
        short8 b2 = Bb[(size_t)kk * 256 + 32];
        short8 b3 = Bb[(size_t)kk * 256 + 48];
        acc[0][0] = __builtin_amdgcn_mfma_f32_16x16x32_bf16(a0, b0, acc[0][0], 0, 0, 0);
        acc[0][1] = __builtin_amdgcn_mfma_f32_16x16x32_bf16(a0, b1, acc[0][1], 0, 0, 0);
        acc[0][2] = __builtin_amdgcn_mfma_f32_16x16x32_bf16(a0, b2, acc[0][2], 0, 0, 0);
        acc[0][3] = __builtin_amdgcn_mfma_f32_16x16x32_bf16(a0, b3, acc[0][3], 0, 0, 0);
        acc[1][0] = __builtin_amdgcn_mfma_f32_16x16x32_bf16(a1, b0, acc[1][0], 0, 0, 0);
        acc[1][1] = __builtin_amdgcn_mfma_f32_16x16x32_bf16(a1, b1, acc[1][1], 0, 0, 0);
        acc[1][2] = __builtin_amdgcn_mfma_f32_16x16x32_bf16(a1, b2, acc[1][2], 0, 0, 0);
        acc[1][3] = __builtin_amdgcn_mfma_f32_16x16x32_bf16(a1, b3, acc[1][3], 0, 0, 0);
        acc[2][0] = __builtin_amdgcn_mfma_f32_16x16x32_bf16(a2, b0, acc[2][0], 0, 0, 0);
        acc[2][1] = __builtin_amdgcn_mfma_f32_16x16x32_bf16(a2, b1, acc[2][1], 0, 0, 0);
        acc[2][2] = __builtin_amdgcn_mfma_f32_16x16x32_bf16(a2, b2, acc[2][2], 0, 0, 0);
        acc[2][3] = __builtin_amdgcn_mfma_f32_16x16x32_bf16(a2, b3, acc[2][3], 0, 0, 0);
        acc[3][0] = __builtin_amdgcn_mfma_f32_16x16x32_bf16(a3, b0, acc[3][0], 0, 0, 0);
        acc[3][1] = __builtin_amdgcn_mfma_f32_16x16x32_bf16(a3, b1, acc[3][1], 0, 0, 0);
        acc[3][2] = __builtin_amdgcn_mfma_f32_16x16x32_bf16(a3, b2, acc[3][2], 0, 0, 0);
        acc[3][3] = __builtin_amdgcn_mfma_f32_16x16x32_bf16(a3, b3, acc[3][3], 0, 0, 0);
    }

    // store xp tile (fp8, HW packed encode): D row = m0+mr*16+q*4+r, col = n0+nc*16+t
    unsigned char* Cr = C + n0 + t;
#pragma unroll
    for (int mr = 0; mr < 4; mr++) {
#pragma unroll
        for (int r = 0; r < 4; r++) {
            int row = m0 + mr * 16 + q * 4 + r;
            if (row < M) {
                size_t ro = (size_t)row * 256;
                unsigned pk = fp8x4_encode(acc[mr][0][r], acc[mr][1][r],
                                           acc[mr][2][r], acc[mr][3][r]);
                Cr[ro +  0] = (unsigned char)(pk & 0xff);
                Cr[ro + 16] = (unsigned char)((pk >> 8) & 0xff);
                Cr[ro + 32] = (unsigned char)((pk >> 16) & 0xff);
                Cr[ro + 48] = (unsigned char)(pk >> 24);
            }
        }
    }

    // fused scores: per row, sum D[row][col]*a[col] over this wave's 64 cols
    float as[4], an[4];
#pragma unroll
    for (int nc = 0; nc < 4; nc++) {
        as[nc] = a_self[n0 + nc * 16 + t];
        an[nc] = a_neigh[n0 + nc * 16 + t];
    }
#pragma unroll
    for (int mr = 0; mr < 4; mr++) {
#pragma unroll
        for (int r = 0; r < 4; r++) {
            float pes = acc[mr][0][r] * as[0] + acc[mr][1][r] * as[1]
                      + acc[mr][2][r] * as[2] + acc[mr][3][r] * as[3];
            float pen = acc[mr][0][r] * an[0] + acc[mr][1][r] * an[1]
                      + acc[mr][2][r] * an[2] + acc[mr][3][r] * an[3];
#pragma unroll
            for (int mask = 1; mask < 16; mask <<= 1) {
                pes += __shfl_xor(pes, mask);
                pen += __shfl_xor(pen, mask);
            }
            if (t == 0) {
                int row = m0 + mr * 16 + q * 4 + r;
                if (row < M) {
                    es[(size_t)row * 4 + wv] = pes;
                    en[(size_t)row * 4 + wv] = pen;
                }
            }
        }
    }
}

// ---------- fused softmax + aggregation: one wave per node (R9-verified) ----------
// mode: partials==nullptr -> write per-node bf16 rows to out;
//       else -> apply bias+selu, LDS-reduce the block's 4 nodes, write one
//       f32 row per block to partials (layer-2: h2 only feeds the sum-pool).
__global__ __launch_bounds__(256) void aggregate(const unsigned char* __restrict__ xp,
                                                 const float* __restrict__ es,
                                                 const float* __restrict__ en,
                                                 const int* __restrict__ cursor,
                                                 const int* __restrict__ ssrc,
                                                 const float* __restrict__ bias,
                                                 ushort* __restrict__ out,
                                                 float* __restrict__ partials, int N) {
    __shared__ float part[4][256];
    int wave = (blockIdx.x * blockDim.x + threadIdx.x) >> 6;
    int wv = (threadIdx.x >> 6) & 3;
    int lane = threadIdx.x & 63;
    if (wave >= N) return;                  // grid exact: never taken
    int n = wave;
    int e0 = n * SLOT_CAP;
    int deg = cursor[n]; deg = (deg > SLOT_CAP) ? SLOT_CAP : deg;
    int e1 = e0 + deg;
    int h = lane >> 4;                 // lane's head (channels lane*4..lane*4+3)
    int c0 = lane * 4;
    float esh = es[(size_t)n * 4 + h];
    float dd = 0.f;
    float a0 = 0.f, a1 = 0.f, a2 = 0.f, a3 = 0.f;
    float b0 = 0.f, b1 = 0.f, b2 = 0.f, b3 = 0.f;
    int e = e0;
    for (; e + 1 < e1; e += 2) {
        int sA = __builtin_amdgcn_readfirstlane(ssrc[e]);
        int sB = __builtin_amdgcn_readfirstlane(ssrc[e + 1]);
        float evA = __expf(lrelu_f(esh + en[(size_t)sA * 4 + h]));
        float evB = __expf(lrelu_f(esh + en[(size_t)sB * 4 + h]));
        unsigned uA = *(const unsigned*)(xp + (size_t)sA * 256 + c0);
        unsigned uB = *(const unsigned*)(xp + (size_t)sB * 256 + c0);
        dd += evA + evB;
        float fA[4], fB[4];
        fp8x4_decode(uA, fA);
        fp8x4_decode(uB, fB);
        a0 += evA * fA[0]; a1 += evA * fA[1]; a2 += evA * fA[2]; a3 += evA * fA[3];
        b0 += evB * fB[0]; b1 += evB * fB[1]; b2 += evB * fB[2]; b3 += evB * fB[3];
    }
    if (e < e1) {
        int s = __builtin_amdgcn_readfirstlane(ssrc[e]);
        float ev = __expf(lrelu_f(esh + en[(size_t)s * 4 + h]));
        unsigned u = *(const unsigned*)(xp + (size_t)s * 256 + c0);
        dd += ev;
        float f[4];
        fp8x4_decode(u, f);
        a0 += ev * f[0]; a1 += ev * f[1]; a2 += ev * f[2]; a3 += ev * f[3];
    }
    float inv = (dd > 0.f) ? 1.f / dd : 0.f;
    float4 bb = *(const float4*)(bias + c0);
    float r0 = selu_f((a0 + b0) * inv + bb.x);
    float r1 = selu_f((a1 + b1) * inv + bb.y);
    float r2 = selu_f((a2 + b2) * inv + bb.z);
    float r3 = selu_f((a3 + b3) * inv + bb.w);
    if (partials == nullptr) {
        ushort r[4] = { f2bf(r0), f2bf(r1), f2bf(r2), f2bf(r3) };
        *(uint2*)(out + (size_t)n * 256 + c0) = *(uint2*)r;
    } else {
        part[wv][c0 + 0] = r0; part[wv][c0 + 1] = r1;
        part[wv][c0 + 2] = r2; part[wv][c0 + 3] = r3;
        __syncthreads();
        if (wv == 0) {
            float4 s;
            s.x = r0 + part[1][c0 + 0] + part[2][c0 + 0] + part[3][c0 + 0];
            s.y = r1 + part[1][c0 + 1] + part[2][c0 + 1] + part[3][c0 + 1];
            s.z = r2 + part[1][c0 + 2] + part[2][c0 + 2] + part[3][c0 + 2];
            s.w = r3 + part[1][c0 + 3] + part[2][c0 + 3] + part[3][c0 + 3];
            *(float4*)(partials + (size_t)blockIdx.x * 256 + c0) = s;
        }
    }
}

// ---------- reduce per-block partials [R][256] -> g[256] ----------
__global__ __launch_bounds__(256) void colsum_part(const float* __restrict__ p,
                                                   float* __restrict__ g, int R) {
    __shared__ float part[4][256];
    int tid = threadIdx.x;
    int rg = tid >> 6;            // row group 0..3
    int c0 = (tid & 63) * 4;      // channel group
    float4 acc = {0.f, 0.f, 0.f, 0.f};
    for (int r = blockIdx.x * 4 + rg; r < R; r += gridDim.x * 4) {
        float4 v = *(const float4*)(p + (size_t)r * 256 + c0);
        acc.x += v.x; acc.y += v.y; acc.z += v.z; acc.w += v.w;
    }
    *(float4*)(&part[rg][c0]) = acc;
    __syncthreads();
    if (rg == 0) {
        float4 s = acc;
        for (int r = 1; r < 4; r++) {
            s.x += part[r][c0 + 0]; s.y += part[r][c0 + 1];
            s.z += part[r][c0 + 2]; s.w += part[r][c0 + 3];
        }
        atomicAdd(&g[c0 + 0], s.x);
        atomicAdd(&g[c0 + 1], s.y);
        atomicAdd(&g[c0 + 2], s.z);
        atomicAdd(&g[c0 + 3], s.w);
    }
}

// ---------- MLP head, single block ----------
__global__ __launch_bounds__(256) void mlp_head(const float* __restrict__ g,
                                                const float* __restrict__ Wd1, const float* __restrict__ bd1,
                                                const float* __restrict__ Wd2, const float* __restrict__ bd2,
                                                const float* __restrict__ Wo, const float* __restrict__ bo,
                                                float* __restrict__ out) {
    __shared__ float sg[256], y1[64], y2[32];
    int t = threadIdx.x;
    sg[t] = g[t];
    __syncthreads();
    if (t < 64) {
        float s = bd1[t];
        for (int k = 0; k < 256; k++) s += sg[k] * Wd1[k * 64 + t];
        y1[t] = selu_f(s);
    }
    __syncthreads();
    if (t < 32) {
        float s = bd2[t];
        for (int k = 0; k < 64; k++) s += y1[k] * Wd2[k * 32 + t];
        y2[t] = selu_f(s);
    }
    __syncthreads();
    if (t == 0) {
        float s = bo[0];
        for (int k = 0; k < 32; k++) s += y2[k] * Wo[k];
        out[0] = s;
    }
}

// ---------- host launcher ----------
extern "C" void kernel_launch(void* const* d_in, const int* in_sizes, int n_in,
                              void* d_out, int out_size, void* d_ws, size_t ws_size,
                              hipStream_t stream) {
    const float* x   = (const float*)d_in[0];
    const int*   ei  = (const int*)d_in[1];
    const float* W1  = (const float*)d_in[2];
    const float* as1 = (const float*)d_in[3];
    const float* an1 = (const float*)d_in[4];
    const float* b1  = (const float*)d_in[5];
    const float* W2  = (const float*)d_in[6];
    const float* as2 = (const float*)d_in[7];
    const float* an2 = (const float*)d_in[8];
    const float* b2  = (const float*)d_in[9];
    const float* Wd1 = (const float*)d_in[10];
    const float* bd1 = (const float*)d_in[11];
    const float* Wd2 = (const float*)d_in[12];
    const float* bd2 = (const float*)d_in[13];
    const float* Wo  = (const float*)d_in[14];
    const float* bo  = (const float*)d_in[15];
    const int* tgt  = ei;
    const int* srcp = ei + N_EDGES;

    char* w = (char*)d_ws;
    size_t off_b = 0;
    auto alloc = [&](size_t bytes) -> void* {
        void* p = w + off_b;
        off_b = (off_b + bytes + 255) & ~(size_t)255;
        return p;
    };
    ushort* Apx  = (ushort*)alloc((size_t)N_NODES * 128 * 2);       // x in bf16
    ushort* Bp1  = (ushort*)alloc((size_t)128 * 256 * 2);           // W1 packed
    ushort* Bp2  = (ushort*)alloc((size_t)256 * 256 * 2);           // W2 packed
    unsigned char* xp8 = (unsigned char*)alloc((size_t)N_NODES * 256); // projection, fp8
    ushort* h1b  = (ushort*)alloc((size_t)N_NODES * 256 * 2);       // h1 (bf16)
    float* es    = (float*)alloc((size_t)N_NODES * 4 * 4);
    float* en    = (float*)alloc((size_t)N_NODES * 4 * 4);
    int*   cursor= (int*)alloc((size_t)N_NODES * 4);
    int*   ssrc  = (int*)alloc((size_t)N_NODES * SLOT_CAP * 4);     // slot-CSR (19.2 MB)
    float* pp    = (float*)alloc((size_t)AGG_BLOCKS * 256 * 4);     // layer-2 block partials
    float* g     = (float*)alloc(1024);

    const int EB = (N_EDGES + 255) / 256;
    const int GB = (N_NODES + 63) / 64;    // 782 gemm blocks

    // ===== pack + init (1 launch) =====
    pack_all<<<(N_NODES * 128 / 8 + 255) / 256, 256, 0, stream>>>(
        x, Apx, W1, Bp1, W2, Bp2, cursor, g);

    // ===== slot-CSR build (1 launch) =====
    edge_scatter<<<EB, 256, 0, stream>>>(tgt, srcp, cursor, ssrc, N_EDGES);

    // ===== layer 1 =====
    gemm_scores<<<GB, 256, 0, stream>>>((const short8*)Apx, (const short8*)Bp1,
                                        xp8, as1, an1, es, en, 16, N_NODES);
    aggregate<<<AGG_BLOCKS, 256, 0, stream>>>(xp8, es, en, cursor, ssrc, b1, h1b, nullptr, N_NODES);

    // ===== layer 2 =====
    gemm_scores<<<GB, 256, 0, stream>>>((const short8*)h1b, (const short8*)Bp2,
                                        xp8, as2, an2, es, en, 32, N_NODES);
    aggregate<<<AGG_BLOCKS, 256, 0, stream>>>(xp8, es, en, cursor, ssrc, b2, nullptr, pp, N_NODES);

    // ===== pool + MLP =====
    colsum_part<<<128, 256, 0, stream>>>(pp, g, AGG_BLOCKS);
    mlp_head<<<1, 256, 0, stream>>>(g, Wd1, bd1, Wd2, bd2, Wo, bo, (float*)d_out);
}

// Round 13
// 296.801 us; speedup vs baseline: 1.2442x; 1.1391x over previous
//
#include <hip/hip_runtime.h>
#include <hip/hip_bf16.h>
#include <hip/hip_fp8.h>
#include <math.h>

#define N_NODES 50000
#define N_EDGES 800000
#define SLOT_CAP 96                     // max in-degree slots per node (E[deg]=16, max<~50)
#define AGG_BLOCKS (N_NODES / 4)        // 12500 aggregate blocks (4 nodes each)

typedef __attribute__((ext_vector_type(8))) short short8;   // 8 x bf16 (4 VGPRs)
typedef __attribute__((ext_vector_type(4))) float f32x4;    // MFMA accumulator
typedef __attribute__((ext_vector_type(2))) float f32x2;

// ---------- device helpers ----------
__device__ __forceinline__ float selu_f(float x) {
    const float scale = 1.0507009873554805f;
    const float alpha = 1.6732632423543772f;
    return x > 0.f ? scale * x : scale * alpha * (expf(x) - 1.f);
}
__device__ __forceinline__ float lrelu_f(float x) {
    return x >= 0.f ? x : 0.2f * x;
}
__device__ __forceinline__ ushort f2bf(float f) {
    __hip_bfloat16 h = __float2bfloat16(f);   // RNE
    return *(ushort*)&h;
}
__device__ __forceinline__ unsigned char f2fp8(float f) {
    __hip_fp8_e4m3 q(f);                       // OCP e4m3, RNE+sat (software fallback)
    return (unsigned char)q.__x;
}
__device__ __forceinline__ float fp82f(unsigned char b) {
    __hip_fp8_e4m3 q; q.__x = (__hip_fp8_storage_t)b;
    return (float)q;
}
// decode 4 packed fp8 (one dword) -> 4 floats
__device__ __forceinline__ void fp8x4_decode(unsigned u, float* o) {
#if __has_builtin(__builtin_amdgcn_cvt_pk_f32_fp8)
    f32x2 lo = __builtin_amdgcn_cvt_pk_f32_fp8((int)u, false);
    f32x2 hi = __builtin_amdgcn_cvt_pk_f32_fp8((int)u, true);
    o[0] = lo.x; o[1] = lo.y; o[2] = hi.x; o[3] = hi.y;
#else
    o[0] = fp82f(u & 0xff);
    o[1] = fp82f((u >> 8) & 0xff);
    o[2] = fp82f((u >> 16) & 0xff);
    o[3] = fp82f(u >> 24);
#endif
}
// encode 4 floats -> packed fp8 dword (HW v_cvt_pk_fp8_f32)
__device__ __forceinline__ unsigned fp8x4_encode(float f0, float f1, float f2, float f3) {
#if __has_builtin(__builtin_amdgcn_cvt_pk_fp8_f32)
    int v = 0;
    v = __builtin_amdgcn_cvt_pk_fp8_f32(f0, f1, v, false);
    v = __builtin_amdgcn_cvt_pk_fp8_f32(f2, f3, v, true);
    return (unsigned)v;
#else
    return (unsigned)f2fp8(f0) | ((unsigned)f2fp8(f1) << 8) |
           ((unsigned)f2fp8(f2) << 16) | ((unsigned)f2fp8(f3) << 24);
#endif
}

// ---------- fused pack + init (once per call) ----------
__global__ void pack_all(const float* __restrict__ x, ushort* __restrict__ Apx,
                         const float* __restrict__ W1, ushort* __restrict__ Bp1,
                         const float* __restrict__ W2, ushort* __restrict__ Bp2,
                         int* __restrict__ cursor, float* __restrict__ g) {
    int i = blockIdx.x * blockDim.x + threadIdx.x;
    if (i < N_NODES * 128 / 8) {
        const float4* p = (const float4*)x + (size_t)i * 2;
        float4 a = p[0], b = p[1];
        ushort u[8] = { f2bf(a.x), f2bf(a.y), f2bf(a.z), f2bf(a.w),
                        f2bf(b.x), f2bf(b.y), f2bf(b.z), f2bf(b.w) };
        *(uint4*)(Apx + (size_t)i * 8) = *(uint4*)u;
    }
    if (i < 16 * 256) {                     // W1: K8 = 16
        int kg = i >> 8, n = i & 255;
        ushort u[8];
#pragma unroll
        for (int j = 0; j < 8; j++) u[j] = f2bf(W1[(size_t)(kg * 8 + j) * 256 + n]);
        *(uint4*)(Bp1 + ((size_t)kg * 256 + n) * 8) = *(uint4*)u;
    }
    if (i < 32 * 256) {                     // W2: K8 = 32
        int kg = i >> 8, n = i & 255;
        ushort u[8];
#pragma unroll
        for (int j = 0; j < 8; j++) u[j] = f2bf(W2[(size_t)(kg * 8 + j) * 256 + n]);
        *(uint4*)(Bp2 + ((size_t)kg * 256 + n) * 8) = *(uint4*)u;
    }
    if (i < N_NODES) cursor[i] = 0;
    if (i < 256) g[i] = 0.f;
}

// ---------- gemm body (shared by union + standalone kernels) ----------
// 64-row block tile, LDS-staged A, fused scores; xp stored fp8.
// Fragment layouts (guide §3, m89/m91-verified): A[m=lane&15][k=quad*8+j],
// B[k=quad*8+j][n=lane&15], D col=lane&15 row=quad*4+reg.
__device__ __forceinline__ void gemm_body(int blk,
                                          const short8* __restrict__ A,
                                          const short8* __restrict__ B,
                                          unsigned char* __restrict__ C,
                                          const float* __restrict__ a_self,
                                          const float* __restrict__ a_neigh,
                                          float* __restrict__ es,
                                          float* __restrict__ en,
                                          int K8, int M) {
    __shared__ short8 Atile[64][5];        // [row][chunk 0..3], +1 pad (80B row stride)
    const int tid = threadIdx.x;
    const int wv = tid >> 6, lane = tid & 63;
    const int q = lane >> 4, t = lane & 15;
    const int m0 = blk * 64;
    const int n0 = wv * 64;

    const int srow = tid >> 2, sc = tid & 3;
    int grow = m0 + srow; if (grow > M - 1) grow = M - 1;   // row clamp (stores guarded)
    const short8* Ag = A + (size_t)grow * K8 + sc;

    f32x4 acc[4][4];
#pragma unroll
    for (int mr = 0; mr < 4; mr++)
#pragma unroll
        for (int nc = 0; nc < 4; nc++) acc[mr][nc] = (f32x4){0.f, 0.f, 0.f, 0.f};

    const short8* Bb = B + (size_t)q * 256 + n0 + t;
    for (int kk = 0; kk < K8; kk += 4) {       // 32 k per step
        __syncthreads();
        Atile[srow][sc] = Ag[kk];
        __syncthreads();
        short8 a0 = Atile[t][q];
        short8 a1 = Atile[16 + t][q];
        short8 a2 = Atile[32 + t][q];
        short8 a3 = Atile[48 + t][q];
        short8 b0 = Bb[(size_t)kk * 256 + 0];
        short8 b1 = Bb[(size_t)kk * 256 + 16];
        short8 b2 = Bb[(size_t)kk * 256 + 32];
        short8 b3 = Bb[(size_t)kk * 256 + 48];
        acc[0][0] = __builtin_amdgcn_mfma_f32_16x16x32_bf16(a0, b0, acc[0][0], 0, 0, 0);
        acc[0][1] = __builtin_amdgcn_mfma_f32_16x16x32_bf16(a0, b1, acc[0][1], 0, 0, 0);
        acc[0][2] = __builtin_amdgcn_mfma_f32_16x16x32_bf16(a0, b2, acc[0][2], 0, 0, 0);
        acc[0][3] = __builtin_amdgcn_mfma_f32_16x16x32_bf16(a0, b3, acc[0][3], 0, 0, 0);
        acc[1][0] = __builtin_amdgcn_mfma_f32_16x16x32_bf16(a1, b0, acc[1][0], 0, 0, 0);
        acc[1][1] = __builtin_amdgcn_mfma_f32_16x16x32_bf16(a1, b1, acc[1][1], 0, 0, 0);
        acc[1][2] = __builtin_amdgcn_mfma_f32_16x16x32_bf16(a1, b2, acc[1][2], 0, 0, 0);
        acc[1][3] = __builtin_amdgcn_mfma_f32_16x16x32_bf16(a1, b3, acc[1][3], 0, 0, 0);
        acc[2][0] = __builtin_amdgcn_mfma_f32_16x16x32_bf16(a2, b0, acc[2][0], 0, 0, 0);
        acc[2][1] = __builtin_amdgcn_mfma_f32_16x16x32_bf16(a2, b1, acc[2][1], 0, 0, 0);
        acc[2][2] = __builtin_amdgcn_mfma_f32_16x16x32_bf16(a2, b2, acc[2][2], 0, 0, 0);
        acc[2][3] = __builtin_amdgcn_mfma_f32_16x16x32_bf16(a2, b3, acc[2][3], 0, 0, 0);
        acc[3][0] = __builtin_amdgcn_mfma_f32_16x16x32_bf16(a3, b0, acc[3][0], 0, 0, 0);
        acc[3][1] = __builtin_amdgcn_mfma_f32_16x16x32_bf16(a3, b1, acc[3][1], 0, 0, 0);
        acc[3][2] = __builtin_amdgcn_mfma_f32_16x16x32_bf16(a3, b2, acc[3][2], 0, 0, 0);
        acc[3][3] = __builtin_amdgcn_mfma_f32_16x16x32_bf16(a3, b3, acc[3][3], 0, 0, 0);
    }

    unsigned char* Cr = C + n0 + t;
#pragma unroll
    for (int mr = 0; mr < 4; mr++) {
#pragma unroll
        for (int r = 0; r < 4; r++) {
            int row = m0 + mr * 16 + q * 4 + r;
            if (row < M) {
                size_t ro = (size_t)row * 256;
                unsigned pk = fp8x4_encode(acc[mr][0][r], acc[mr][1][r],
                                           acc[mr][2][r], acc[mr][3][r]);
                Cr[ro +  0] = (unsigned char)(pk & 0xff);
                Cr[ro + 16] = (unsigned char)((pk >> 8) & 0xff);
                Cr[ro + 32] = (unsigned char)((pk >> 16) & 0xff);
                Cr[ro + 48] = (unsigned char)(pk >> 24);
            }
        }
    }

    float as[4], an[4];
#pragma unroll
    for (int nc = 0; nc < 4; nc++) {
        as[nc] = a_self[n0 + nc * 16 + t];
        an[nc] = a_neigh[n0 + nc * 16 + t];
    }
#pragma unroll
    for (int mr = 0; mr < 4; mr++) {
#pragma unroll
        for (int r = 0; r < 4; r++) {
            float pes = acc[mr][0][r] * as[0] + acc[mr][1][r] * as[1]
                      + acc[mr][2][r] * as[2] + acc[mr][3][r] * as[3];
            float pen = acc[mr][0][r] * an[0] + acc[mr][1][r] * an[1]
                      + acc[mr][2][r] * an[2] + acc[mr][3][r] * an[3];
#pragma unroll
            for (int mask = 1; mask < 16; mask <<= 1) {
                pes += __shfl_xor(pes, mask);
                pen += __shfl_xor(pen, mask);
            }
            if (t == 0) {
                int row = m0 + mr * 16 + q * 4 + r;
                if (row < M) {
                    es[(size_t)row * 4 + wv] = pes;
                    en[(size_t)row * 4 + wv] = pen;
                }
            }
        }
    }
}

// ---------- union kernel: scatter blocks [0,EB) + gemm layer-1 blocks [EB,EB+GB) ----------
// Independent work fused into one launch: the latency-bound atomic scatter
// hides behind gemm compute (~2000 blocks co-resident).
__global__ __launch_bounds__(256) void scatter_gemm1(const int* __restrict__ tgt,
                                                     const int* __restrict__ src,
                                                     int* __restrict__ cursor,
                                                     int* __restrict__ ssrc, int E, int EB,
                                                     const short8* __restrict__ A,
                                                     const short8* __restrict__ B,
                                                     unsigned char* __restrict__ C,
                                                     const float* __restrict__ a_self,
                                                     const float* __restrict__ a_neigh,
                                                     float* __restrict__ es,
                                                     float* __restrict__ en,
                                                     int K8, int M) {
    if ((int)blockIdx.x < EB) {
        int e = blockIdx.x * 256 + threadIdx.x;
        if (e < E) {
            int t = tgt[e];
            int r = atomicAdd(&cursor[t], 1);
            if (r < SLOT_CAP) ssrc[(size_t)t * SLOT_CAP + r] = src[e];
        }
        return;
    }
    gemm_body(blockIdx.x - EB, A, B, C, a_self, a_neigh, es, en, K8, M);
}

// ---------- standalone gemm (layer 2) ----------
__global__ __launch_bounds__(256) void gemm_scores(const short8* __restrict__ A,
                                                   const short8* __restrict__ B,
                                                   unsigned char* __restrict__ C,
                                                   const float* __restrict__ a_self,
                                                   const float* __restrict__ a_neigh,
                                                   float* __restrict__ es,
                                                   float* __restrict__ en,
                                                   int K8, int M) {
    gemm_body(blockIdx.x, A, B, C, a_self, a_neigh, es, en, K8, M);
}

// ---------- fused softmax + aggregation: one wave per node ----------
// R13: ssrc segment preloaded into one register (lane-indexed), distributed via
// dynamic __shfl (no memory chain), 4-edge unroll -> 8 independent gathers in
// flight. Tail (deg>64, essentially never) uses direct loads.
// mode: partials==nullptr -> per-node bf16 rows; else bias+selu + LDS-reduce
// the block's 4 nodes -> one f32 row per block (layer-2 feeds only sum-pool).
__global__ __launch_bounds__(256) void aggregate(const unsigned char* __restrict__ xp,
                                                 const float* __restrict__ es,
                                                 const float* __restrict__ en,
                                                 const int* __restrict__ cursor,
                                                 const int* __restrict__ ssrc,
                                                 const float* __restrict__ bias,
                                                 ushort* __restrict__ out,
                                                 float* __restrict__ partials, int N) {
    __shared__ float part[4][256];
    int wave = (blockIdx.x * blockDim.x + threadIdx.x) >> 6;
    int wv = (threadIdx.x >> 6) & 3;
    int lane = threadIdx.x & 63;
    if (wave >= N) return;                  // grid exact: never taken
    int n = wave;
    int e0 = n * SLOT_CAP;
    int deg = cursor[n]; deg = (deg > SLOT_CAP) ? SLOT_CAP : deg;
    int h = lane >> 4;                 // lane's head (channels lane*4..lane*4+3)
    int c0 = lane * 4;
    float esh = es[(size_t)n * 4 + h];
    float dd = 0.f;
    float a0 = 0.f, a1 = 0.f, a2 = 0.f, a3 = 0.f;

    int dmain = (deg > 64) ? 64 : deg;
    int sv = (lane < dmain) ? ssrc[e0 + lane] : 0;   // whole segment in 1 coalesced load
    int i = 0;
    for (; i + 3 < dmain; i += 4) {
        int sA = __shfl(sv, i);
        int sB = __shfl(sv, i + 1);
        int sC = __shfl(sv, i + 2);
        int sD = __shfl(sv, i + 3);
        float eA = en[(size_t)sA * 4 + h];
        float eB = en[(size_t)sB * 4 + h];
        float eC = en[(size_t)sC * 4 + h];
        float eD = en[(size_t)sD * 4 + h];
        unsigned uA = *(const unsigned*)(xp + (size_t)sA * 256 + c0);
        unsigned uB = *(const unsigned*)(xp + (size_t)sB * 256 + c0);
        unsigned uC = *(const unsigned*)(xp + (size_t)sC * 256 + c0);
        unsigned uD = *(const unsigned*)(xp + (size_t)sD * 256 + c0);
        float evA = __expf(lrelu_f(esh + eA));
        float evB = __expf(lrelu_f(esh + eB));
        float evC = __expf(lrelu_f(esh + eC));
        float evD = __expf(lrelu_f(esh + eD));
        dd += (evA + evB) + (evC + evD);
        float fA[4], fB[4], fC[4], fD[4];
        fp8x4_decode(uA, fA);
        fp8x4_decode(uB, fB);
        fp8x4_decode(uC, fC);
        fp8x4_decode(uD, fD);
        a0 += evA * fA[0] + evB * fB[0] + evC * fC[0] + evD * fD[0];
        a1 += evA * fA[1] + evB * fB[1] + evC * fC[1] + evD * fD[1];
        a2 += evA * fA[2] + evB * fB[2] + evC * fC[2] + evD * fD[2];
        a3 += evA * fA[3] + evB * fB[3] + evC * fC[3] + evD * fD[3];
    }
    for (; i < dmain; i++) {
        int s = __shfl(sv, i);
        float ev = __expf(lrelu_f(esh + en[(size_t)s * 4 + h]));
        unsigned u = *(const unsigned*)(xp + (size_t)s * 256 + c0);
        dd += ev;
        float f[4];
        fp8x4_decode(u, f);
        a0 += ev * f[0]; a1 += ev * f[1]; a2 += ev * f[2]; a3 += ev * f[3];
    }
    // tail: deg > 64 (statistically absent at Poisson(16); correctness guard)
    for (int e = e0 + 64; e < e0 + deg; e++) {
        int s = __builtin_amdgcn_readfirstlane(ssrc[e]);
        float ev = __expf(lrelu_f(esh + en[(size_t)s * 4 + h]));
        unsigned u = *(const unsigned*)(xp + (size_t)s * 256 + c0);
        dd += ev;
        float f[4];
        fp8x4_decode(u, f);
        a0 += ev * f[0]; a1 += ev * f[1]; a2 += ev * f[2]; a3 += ev * f[3];
    }

    float inv = (dd > 0.f) ? 1.f / dd : 0.f;
    float4 bb = *(const float4*)(bias + c0);
    float r0 = selu_f(a0 * inv + bb.x);
    float r1 = selu_f(a1 * inv + bb.y);
    float r2 = selu_f(a2 * inv + bb.z);
    float r3 = selu_f(a3 * inv + bb.w);
    if (partials == nullptr) {
        ushort r[4] = { f2bf(r0), f2bf(r1), f2bf(r2), f2bf(r3) };
        *(uint2*)(out + (size_t)n * 256 + c0) = *(uint2*)r;
    } else {
        part[wv][c0 + 0] = r0; part[wv][c0 + 1] = r1;
        part[wv][c0 + 2] = r2; part[wv][c0 + 3] = r3;
        __syncthreads();
        if (wv == 0) {
            float4 s;
            s.x = r0 + part[1][c0 + 0] + part[2][c0 + 0] + part[3][c0 + 0];
            s.y = r1 + part[1][c0 + 1] + part[2][c0 + 1] + part[3][c0 + 1];
            s.z = r2 + part[1][c0 + 2] + part[2][c0 + 2] + part[3][c0 + 2];
            s.w = r3 + part[1][c0 + 3] + part[2][c0 + 3] + part[3][c0 + 3];
            *(float4*)(partials + (size_t)blockIdx.x * 256 + c0) = s;
        }
    }
}

// ---------- reduce per-block partials [R][256] -> g[256] ----------
__global__ __launch_bounds__(256) void colsum_part(const float* __restrict__ p,
                                                   float* __restrict__ g, int R) {
    __shared__ float part[4][256];
    int tid = threadIdx.x;
    int rg = tid >> 6;            // row group 0..3
    int c0 = (tid & 63) * 4;      // channel group
    float4 acc = {0.f, 0.f, 0.f, 0.f};
    for (int r = blockIdx.x * 4 + rg; r < R; r += gridDim.x * 4) {
        float4 v = *(const float4*)(p + (size_t)r * 256 + c0);
        acc.x += v.x; acc.y += v.y; acc.z += v.z; acc.w += v.w;
    }
    *(float4*)(&part[rg][c0]) = acc;
    __syncthreads();
    if (rg == 0) {
        float4 s = acc;
        for (int r = 1; r < 4; r++) {
            s.x += part[r][c0 + 0]; s.y += part[r][c0 + 1];
            s.z += part[r][c0 + 2]; s.w += part[r][c0 + 3];
        }
        atomicAdd(&g[c0 + 0], s.x);
        atomicAdd(&g[c0 + 1], s.y);
        atomicAdd(&g[c0 + 2], s.z);
        atomicAdd(&g[c0 + 3], s.w);
    }
}

// ---------- MLP head, single block ----------
__global__ __launch_bounds__(256) void mlp_head(const float* __restrict__ g,
                                                const float* __restrict__ Wd1, const float* __restrict__ bd1,
                                                const float* __restrict__ Wd2, const float* __restrict__ bd2,
                                                const float* __restrict__ Wo, const float* __restrict__ bo,
                                                float* __restrict__ out) {
    __shared__ float sg[256], y1[64], y2[32];
    int t = threadIdx.x;
    sg[t] = g[t];
    __syncthreads();
    if (t < 64) {
        float s = bd1[t];
        for (int k = 0; k < 256; k++) s += sg[k] * Wd1[k * 64 + t];
        y1[t] = selu_f(s);
    }
    __syncthreads();
    if (t < 32) {
        float s = bd2[t];
        for (int k = 0; k < 64; k++) s += y1[k] * Wd2[k * 32 + t];
        y2[t] = selu_f(s);
    }
    __syncthreads();
    if (t == 0) {
        float s = bo[0];
        for (int k = 0; k < 32; k++) s += y2[k] * Wo[k];
        out[0] = s;
    }
}

// ---------- host launcher ----------
extern "C" void kernel_launch(void* const* d_in, const int* in_sizes, int n_in,
                              void* d_out, int out_size, void* d_ws, size_t ws_size,
                              hipStream_t stream) {
    const float* x   = (const float*)d_in[0];
    const int*   ei  = (const int*)d_in[1];
    const float* W1  = (const float*)d_in[2];
    const float* as1 = (const float*)d_in[3];
    const float* an1 = (const float*)d_in[4];
    const float* b1  = (const float*)d_in[5];
    const float* W2  = (const float*)d_in[6];
    const float* as2 = (const float*)d_in[7];
    const float* an2 = (const float*)d_in[8];
    const float* b2  = (const float*)d_in[9];
    const float* Wd1 = (const float*)d_in[10];
    const float* bd1 = (const float*)d_in[11];
    const float* Wd2 = (const float*)d_in[12];
    const float* bd2 = (const float*)d_in[13];
    const float* Wo  = (const float*)d_in[14];
    const float* bo  = (const float*)d_in[15];
    const int* tgt  = ei;
    const int* srcp = ei + N_EDGES;

    char* w = (char*)d_ws;
    size_t off_b = 0;
    auto alloc = [&](size_t bytes) -> void* {
        void* p = w + off_b;
        off_b = (off_b + bytes + 255) & ~(size_t)255;
        return p;
    };
    ushort* Apx  = (ushort*)alloc((size_t)N_NODES * 128 * 2);       // x in bf16
    ushort* Bp1  = (ushort*)alloc((size_t)128 * 256 * 2);           // W1 packed
    ushort* Bp2  = (ushort*)alloc((size_t)256 * 256 * 2);           // W2 packed
    unsigned char* xp8 = (unsigned char*)alloc((size_t)N_NODES * 256); // projection, fp8
    ushort* h1b  = (ushort*)alloc((size_t)N_NODES * 256 * 2);       // h1 (bf16)
    float* es    = (float*)alloc((size_t)N_NODES * 4 * 4);
    float* en    = (float*)alloc((size_t)N_NODES * 4 * 4);
    int*   cursor= (int*)alloc((size_t)N_NODES * 4);
    int*   ssrc  = (int*)alloc((size_t)N_NODES * SLOT_CAP * 4);     // slot-CSR (19.2 MB)
    float* pp    = (float*)alloc((size_t)AGG_BLOCKS * 256 * 4);     // layer-2 block partials
    float* g     = (float*)alloc(1024);

    const int EB = (N_EDGES + 255) / 256;  // 3125 scatter blocks
    const int GB = (N_NODES + 63) / 64;    // 782 gemm blocks

    // ===== pack + init (1 launch) =====
    pack_all<<<(N_NODES * 128 / 8 + 255) / 256, 256, 0, stream>>>(
        x, Apx, W1, Bp1, W2, Bp2, cursor, g);

    // ===== union: slot-CSR scatter + layer-1 gemm (independent; overlap) =====
    scatter_gemm1<<<EB + GB, 256, 0, stream>>>(tgt, srcp, cursor, ssrc, N_EDGES, EB,
                                               (const short8*)Apx, (const short8*)Bp1,
                                               xp8, as1, an1, es, en, 16, N_NODES);
    aggregate<<<AGG_BLOCKS, 256, 0, stream>>>(xp8, es, en, cursor, ssrc, b1, h1b, nullptr, N_NODES);

    // ===== layer 2 =====
    gemm_scores<<<GB, 256, 0, stream>>>((const short8*)h1b, (const short8*)Bp2,
                                        xp8, as2, an2, es, en, 32, N_NODES);
    aggregate<<<AGG_BLOCKS, 256, 0, stream>>>(xp8, es, en, cursor, ssrc, b2, nullptr, pp, N_NODES);

    // ===== pool + MLP =====
    colsum_part<<<128, 256, 0, stream>>>(pp, g, AGG_BLOCKS);
    mlp_head<<<1, 256, 0, stream>>>(g, Wd1, bd1, Wd2, bd2, Wo, bo, (float*)d_out);
}

// Round 14
// 276.290 us; speedup vs baseline: 1.3366x; 1.0742x over previous
//
#include <hip/hip_runtime.h>
#include <hip/hip_bf16.h>
#include <hip/hip_fp8.h>
#include <math.h>

#define N_NODES 50000
#define N_EDGES 800000
#define SLOT_CAP 96                     // max in-degree slots per node (E[deg]=16, max<~50)
#define AGG_BLOCKS (N_NODES / 4)        // 12500 aggregate blocks (4 nodes each)

typedef __attribute__((ext_vector_type(8))) short short8;   // 8 x bf16 (4 VGPRs)
typedef __attribute__((ext_vector_type(4))) float f32x4;    // MFMA accumulator
typedef __attribute__((ext_vector_type(2))) float f32x2;

// ---------- device helpers ----------
__device__ __forceinline__ float selu_f(float x) {
    const float scale = 1.0507009873554805f;
    const float alpha = 1.6732632423543772f;
    return x > 0.f ? scale * x : scale * alpha * (expf(x) - 1.f);
}
__device__ __forceinline__ float lrelu_f(float x) {
    return x >= 0.f ? x : 0.2f * x;
}
__device__ __forceinline__ ushort f2bf(float f) {
    __hip_bfloat16 h = __float2bfloat16(f);   // RNE
    return *(ushort*)&h;
}
__device__ __forceinline__ unsigned char f2fp8(float f) {
    __hip_fp8_e4m3 q(f);                       // OCP e4m3, RNE+sat (software fallback)
    return (unsigned char)q.__x;
}
__device__ __forceinline__ float fp82f(unsigned char b) {
    __hip_fp8_e4m3 q; q.__x = (__hip_fp8_storage_t)b;
    return (float)q;
}
// decode 4 packed fp8 (one dword) -> 4 floats
__device__ __forceinline__ void fp8x4_decode(unsigned u, float* o) {
#if __has_builtin(__builtin_amdgcn_cvt_pk_f32_fp8)
    f32x2 lo = __builtin_amdgcn_cvt_pk_f32_fp8((int)u, false);
    f32x2 hi = __builtin_amdgcn_cvt_pk_f32_fp8((int)u, true);
    o[0] = lo.x; o[1] = lo.y; o[2] = hi.x; o[3] = hi.y;
#else
    o[0] = fp82f(u & 0xff);
    o[1] = fp82f((u >> 8) & 0xff);
    o[2] = fp82f((u >> 16) & 0xff);
    o[3] = fp82f(u >> 24);
#endif
}
// encode 4 floats -> packed fp8 dword (HW v_cvt_pk_fp8_f32)
__device__ __forceinline__ unsigned fp8x4_encode(float f0, float f1, float f2, float f3) {
#if __has_builtin(__builtin_amdgcn_cvt_pk_fp8_f32)
    int v = 0;
    v = __builtin_amdgcn_cvt_pk_fp8_f32(f0, f1, v, false);
    v = __builtin_amdgcn_cvt_pk_fp8_f32(f2, f3, v, true);
    return (unsigned)v;
#else
    return (unsigned)f2fp8(f0) | ((unsigned)f2fp8(f1) << 8) |
           ((unsigned)f2fp8(f2) << 16) | ((unsigned)f2fp8(f3) << 24);
#endif
}

// ---------- slim pack + init (once per call): W packing + state zero ----------
// x is no longer pre-packed — gemm1 converts fp32->bf16 during LDS staging.
__global__ void pack_w_init(const float* __restrict__ W1, ushort* __restrict__ Bp1,
                            const float* __restrict__ W2, ushort* __restrict__ Bp2,
                            int* __restrict__ cursor, float* __restrict__ g) {
    int i = blockIdx.x * blockDim.x + threadIdx.x;
    if (i < 16 * 256) {                     // W1: K8 = 16
        int kg = i >> 8, n = i & 255;
        ushort u[8];
#pragma unroll
        for (int j = 0; j < 8; j++) u[j] = f2bf(W1[(size_t)(kg * 8 + j) * 256 + n]);
        *(uint4*)(Bp1 + ((size_t)kg * 256 + n) * 8) = *(uint4*)u;
    }
    if (i < 32 * 256) {                     // W2: K8 = 32
        int kg = i >> 8, n = i & 255;
        ushort u[8];
#pragma unroll
        for (int j = 0; j < 8; j++) u[j] = f2bf(W2[(size_t)(kg * 8 + j) * 256 + n]);
        *(uint4*)(Bp2 + ((size_t)kg * 256 + n) * 8) = *(uint4*)u;
    }
    if (i < N_NODES) cursor[i] = 0;
    if (i < 256) g[i] = 0.f;
}

// ---------- gemm body (shared by union + standalone kernels) ----------
// 64-row block tile, LDS-staged A (from bf16 A, or fp32 Af32 with inline RNE
// conversion — bit-identical to pre-packing), fused scores; xp stored fp8.
// Fragment layouts (guide §3, m89/m91-verified): A[m=lane&15][k=quad*8+j],
// B[k=quad*8+j][n=lane&15], D col=lane&15 row=quad*4+reg.
__device__ __forceinline__ void gemm_body(int blk,
                                          const short8* __restrict__ A,
                                          const float* __restrict__ Af32,
                                          const short8* __restrict__ B,
                                          unsigned char* __restrict__ C,
                                          const float* __restrict__ a_self,
                                          const float* __restrict__ a_neigh,
                                          float* __restrict__ es,
                                          float* __restrict__ en,
                                          int K8, int M) {
    __shared__ short8 Atile[64][5];        // [row][chunk 0..3], +1 pad (80B row stride)
    const int tid = threadIdx.x;
    const int wv = tid >> 6, lane = tid & 63;
    const int q = lane >> 4, t = lane & 15;
    const int m0 = blk * 64;
    const int n0 = wv * 64;

    const int srow = tid >> 2, sc = tid & 3;
    int grow = m0 + srow; if (grow > M - 1) grow = M - 1;   // row clamp (stores guarded)
    const short8* Ag = (Af32 == nullptr) ? A + (size_t)grow * K8 + sc : nullptr;
    const float*  Agf = (Af32 != nullptr) ? Af32 + (size_t)grow * (K8 * 8) + sc * 8 : nullptr;

    f32x4 acc[4][4];
#pragma unroll
    for (int mr = 0; mr < 4; mr++)
#pragma unroll
        for (int nc = 0; nc < 4; nc++) acc[mr][nc] = (f32x4){0.f, 0.f, 0.f, 0.f};

    const short8* Bb = B + (size_t)q * 256 + n0 + t;
    for (int kk = 0; kk < K8; kk += 4) {       // 32 k per step
        __syncthreads();
        if (Af32 != nullptr) {                 // block-uniform branch
            float4 v0 = *(const float4*)(Agf + (size_t)kk * 8);
            float4 v1 = *(const float4*)(Agf + (size_t)kk * 8 + 4);
            ushort u[8] = { f2bf(v0.x), f2bf(v0.y), f2bf(v0.z), f2bf(v0.w),
                            f2bf(v1.x), f2bf(v1.y), f2bf(v1.z), f2bf(v1.w) };
            Atile[srow][sc] = *(short8*)u;
        } else {
            Atile[srow][sc] = Ag[kk];
        }
        __syncthreads();
        short8 a0 = Atile[t][q];
        short8 a1 = Atile[16 + t][q];
        short8 a2 = Atile[32 + t][q];
        short8 a3 = Atile[48 + t][q];
        short8 b0 = Bb[(size_t)kk * 256 + 0];
        short8 b1 = Bb[(size_t)kk * 256 + 16];
        short8 b2 = Bb[(size_t)kk * 256 + 32];
        short8 b3 = Bb[(size_t)kk * 256 + 48];
        acc[0][0] = __builtin_amdgcn_mfma_f32_16x16x32_bf16(a0, b0, acc[0][0], 0, 0, 0);
        acc[0][1] = __builtin_amdgcn_mfma_f32_16x16x32_bf16(a0, b1, acc[0][1], 0, 0, 0);
        acc[0][2] = __builtin_amdgcn_mfma_f32_16x16x32_bf16(a0, b2, acc[0][2], 0, 0, 0);
        acc[0][3] = __builtin_amdgcn_mfma_f32_16x16x32_bf16(a0, b3, acc[0][3], 0, 0, 0);
        acc[1][0] = __builtin_amdgcn_mfma_f32_16x16x32_bf16(a1, b0, acc[1][0], 0, 0, 0);
        acc[1][1] = __builtin_amdgcn_mfma_f32_16x16x32_bf16(a1, b1, acc[1][1], 0, 0, 0);
        acc[1][2] = __builtin_amdgcn_mfma_f32_16x16x32_bf16(a1, b2, acc[1][2], 0, 0, 0);
        acc[1][3] = __builtin_amdgcn_mfma_f32_16x16x32_bf16(a1, b3, acc[1][3], 0, 0, 0);
        acc[2][0] = __builtin_amdgcn_mfma_f32_16x16x32_bf16(a2, b0, acc[2][0], 0, 0, 0);
        acc[2][1] = __builtin_amdgcn_mfma_f32_16x16x32_bf16(a2, b1, acc[2][1], 0, 0, 0);
        acc[2][2] = __builtin_amdgcn_mfma_f32_16x16x32_bf16(a2, b2, acc[2][2], 0, 0, 0);
        acc[2][3] = __builtin_amdgcn_mfma_f32_16x16x32_bf16(a2, b3, acc[2][3], 0, 0, 0);
        acc[3][0] = __builtin_amdgcn_mfma_f32_16x16x32_bf16(a3, b0, acc[3][0], 0, 0, 0);
        acc[3][1] = __builtin_amdgcn_mfma_f32_16x16x32_bf16(a3, b1, acc[3][1], 0, 0, 0);
        acc[3][2] = __builtin_amdgcn_mfma_f32_16x16x32_bf16(a3, b2, acc[3][2], 0, 0, 0);
        acc[3][3] = __builtin_amdgcn_mfma_f32_16x16x32_bf16(a3, b3, acc[3][3], 0, 0, 0);
    }

    unsigned char* Cr = C + n0 + t;
#pragma unroll
    for (int mr = 0; mr < 4; mr++) {
#pragma unroll
        for (int r = 0; r < 4; r++) {
            int row = m0 + mr * 16 + q * 4 + r;
            if (row < M) {
                size_t ro = (size_t)row * 256;
                unsigned pk = fp8x4_encode(acc[mr][0][r], acc[mr][1][r],
                                           acc[mr][2][r], acc[mr][3][r]);
                Cr[ro +  0] = (unsigned char)(pk & 0xff);
                Cr[ro + 16] = (unsigned char)((pk >> 8) & 0xff);
                Cr[ro + 32] = (unsigned char)((pk >> 16) & 0xff);
                Cr[ro + 48] = (unsigned char)(pk >> 24);
            }
        }
    }

    float as[4], an[4];
#pragma unroll
    for (int nc = 0; nc < 4; nc++) {
        as[nc] = a_self[n0 + nc * 16 + t];
        an[nc] = a_neigh[n0 + nc * 16 + t];
    }
#pragma unroll
    for (int mr = 0; mr < 4; mr++) {
#pragma unroll
        for (int r = 0; r < 4; r++) {
            float pes = acc[mr][0][r] * as[0] + acc[mr][1][r] * as[1]
                      + acc[mr][2][r] * as[2] + acc[mr][3][r] * as[3];
            float pen = acc[mr][0][r] * an[0] + acc[mr][1][r] * an[1]
                      + acc[mr][2][r] * an[2] + acc[mr][3][r] * an[3];
#pragma unroll
            for (int mask = 1; mask < 16; mask <<= 1) {
                pes += __shfl_xor(pes, mask);
                pen += __shfl_xor(pen, mask);
            }
            if (t == 0) {
                int row = m0 + mr * 16 + q * 4 + r;
                if (row < M) {
                    es[(size_t)row * 4 + wv] = pes;
                    en[(size_t)row * 4 + wv] = pen;
                }
            }
        }
    }
}

// ---------- union kernel: scatter + layer-1 gemm, UNIFORMLY INTERLEAVED ----------
// R13 post-mortem: contiguous [scatter|gemm] ranges serialized (scatter blocks
// flood first, MfmaUtil 1.4%). Exact-ratio swizzle: gemm iff floor(bid*GB/T)
// increments; keeps both classes co-resident so atomics hide behind MFMA.
__global__ __launch_bounds__(256) void scatter_gemm1(const int* __restrict__ tgt,
                                                     const int* __restrict__ src,
                                                     int* __restrict__ cursor,
                                                     int* __restrict__ ssrc, int E,
                                                     int GB, int T,
                                                     const float* __restrict__ x,
                                                     const short8* __restrict__ B,
                                                     unsigned char* __restrict__ C,
                                                     const float* __restrict__ a_self,
                                                     const float* __restrict__ a_neigh,
                                                     float* __restrict__ es,
                                                     float* __restrict__ en,
                                                     int K8, int M) {
    int bid = blockIdx.x;
    int gidx = (int)(((long long)bid * GB) / T);
    int gnext = (int)(((long long)(bid + 1) * GB) / T);
    if (gnext == gidx) {
        // scatter block; index = bid - (gemm blocks before bid)
        int sb = bid - gidx;
        int e = sb * 256 + threadIdx.x;
        if (e < E) {
            int t = tgt[e];
            int r = atomicAdd(&cursor[t], 1);
            if (r < SLOT_CAP) ssrc[(size_t)t * SLOT_CAP + r] = src[e];
        }
        return;
    }
    gemm_body(gidx, nullptr, x, B, C, a_self, a_neigh, es, en, K8, M);
}

// ---------- standalone gemm (layer 2, bf16 A) ----------
__global__ __launch_bounds__(256) void gemm_scores(const short8* __restrict__ A,
                                                   const short8* __restrict__ B,
                                                   unsigned char* __restrict__ C,
                                                   const float* __restrict__ a_self,
                                                   const float* __restrict__ a_neigh,
                                                   float* __restrict__ es,
                                                   float* __restrict__ en,
                                                   int K8, int M) {
    gemm_body(blockIdx.x, A, nullptr, B, C, a_self, a_neigh, es, en, K8, M);
}

// ---------- fused softmax + aggregation: one wave per node (R13-verified) ----------
__global__ __launch_bounds__(256) void aggregate(const unsigned char* __restrict__ xp,
                                                 const float* __restrict__ es,
                                                 const float* __restrict__ en,
                                                 const int* __restrict__ cursor,
                                                 const int* __restrict__ ssrc,
                                                 const float* __restrict__ bias,
                                                 ushort* __restrict__ out,
                                                 float* __restrict__ partials, int N) {
    __shared__ float part[4][256];
    int wave = (blockIdx.x * blockDim.x + threadIdx.x) >> 6;
    int wv = (threadIdx.x >> 6) & 3;
    int lane = threadIdx.x & 63;
    if (wave >= N) return;                  // grid exact: never taken
    int n = wave;
    int e0 = n * SLOT_CAP;
    int deg = cursor[n]; deg = (deg > SLOT_CAP) ? SLOT_CAP : deg;
    int h = lane >> 4;                 // lane's head (channels lane*4..lane*4+3)
    int c0 = lane * 4;
    float esh = es[(size_t)n * 4 + h];
    float dd = 0.f;
    float a0 = 0.f, a1 = 0.f, a2 = 0.f, a3 = 0.f;

    int dmain = (deg > 64) ? 64 : deg;
    int sv = (lane < dmain) ? ssrc[e0 + lane] : 0;   // whole segment in 1 coalesced load
    int i = 0;
    for (; i + 3 < dmain; i += 4) {
        int sA = __shfl(sv, i);
        int sB = __shfl(sv, i + 1);
        int sC = __shfl(sv, i + 2);
        int sD = __shfl(sv, i + 3);
        float eA = en[(size_t)sA * 4 + h];
        float eB = en[(size_t)sB * 4 + h];
        float eC = en[(size_t)sC * 4 + h];
        float eD = en[(size_t)sD * 4 + h];
        unsigned uA = *(const unsigned*)(xp + (size_t)sA * 256 + c0);
        unsigned uB = *(const unsigned*)(xp + (size_t)sB * 256 + c0);
        unsigned uC = *(const unsigned*)(xp + (size_t)sC * 256 + c0);
        unsigned uD = *(const unsigned*)(xp + (size_t)sD * 256 + c0);
        float evA = __expf(lrelu_f(esh + eA));
        float evB = __expf(lrelu_f(esh + eB));
        float evC = __expf(lrelu_f(esh + eC));
        float evD = __expf(lrelu_f(esh + eD));
        dd += (evA + evB) + (evC + evD);
        float fA[4], fB[4], fC[4], fD[4];
        fp8x4_decode(uA, fA);
        fp8x4_decode(uB, fB);
        fp8x4_decode(uC, fC);
        fp8x4_decode(uD, fD);
        a0 += evA * fA[0] + evB * fB[0] + evC * fC[0] + evD * fD[0];
        a1 += evA * fA[1] + evB * fB[1] + evC * fC[1] + evD * fD[1];
        a2 += evA * fA[2] + evB * fB[2] + evC * fC[2] + evD * fD[2];
        a3 += evA * fA[3] + evB * fB[3] + evC * fC[3] + evD * fD[3];
    }
    for (; i < dmain; i++) {
        int s = __shfl(sv, i);
        float ev = __expf(lrelu_f(esh + en[(size_t)s * 4 + h]));
        unsigned u = *(const unsigned*)(xp + (size_t)s * 256 + c0);
        dd += ev;
        float f[4];
        fp8x4_decode(u, f);
        a0 += ev * f[0]; a1 += ev * f[1]; a2 += ev * f[2]; a3 += ev * f[3];
    }
    // tail: deg > 64 (statistically absent at Poisson(16); correctness guard)
    for (int e = e0 + 64; e < e0 + deg; e++) {
        int s = __builtin_amdgcn_readfirstlane(ssrc[e]);
        float ev = __expf(lrelu_f(esh + en[(size_t)s * 4 + h]));
        unsigned u = *(const unsigned*)(xp + (size_t)s * 256 + c0);
        dd += ev;
        float f[4];
        fp8x4_decode(u, f);
        a0 += ev * f[0]; a1 += ev * f[1]; a2 += ev * f[2]; a3 += ev * f[3];
    }

    float inv = (dd > 0.f) ? 1.f / dd : 0.f;
    float4 bb = *(const float4*)(bias + c0);
    float r0 = selu_f(a0 * inv + bb.x);
    float r1 = selu_f(a1 * inv + bb.y);
    float r2 = selu_f(a2 * inv + bb.z);
    float r3 = selu_f(a3 * inv + bb.w);
    if (partials == nullptr) {
        ushort r[4] = { f2bf(r0), f2bf(r1), f2bf(r2), f2bf(r3) };
        *(uint2*)(out + (size_t)n * 256 + c0) = *(uint2*)r;
    } else {
        part[wv][c0 + 0] = r0; part[wv][c0 + 1] = r1;
        part[wv][c0 + 2] = r2; part[wv][c0 + 3] = r3;
        __syncthreads();
        if (wv == 0) {
            float4 s;
            s.x = r0 + part[1][c0 + 0] + part[2][c0 + 0] + part[3][c0 + 0];
            s.y = r1 + part[1][c0 + 1] + part[2][c0 + 1] + part[3][c0 + 1];
            s.z = r2 + part[1][c0 + 2] + part[2][c0 + 2] + part[3][c0 + 2];
            s.w = r3 + part[1][c0 + 3] + part[2][c0 + 3] + part[3][c0 + 3];
            *(float4*)(partials + (size_t)blockIdx.x * 256 + c0) = s;
        }
    }
}

// ---------- reduce per-block partials [R][256] -> g[256] ----------
__global__ __launch_bounds__(256) void colsum_part(const float* __restrict__ p,
                                                   float* __restrict__ g, int R) {
    __shared__ float part[4][256];
    int tid = threadIdx.x;
    int rg = tid >> 6;            // row group 0..3
    int c0 = (tid & 63) * 4;      // channel group
    float4 acc = {0.f, 0.f, 0.f, 0.f};
    for (int r = blockIdx.x * 4 + rg; r < R; r += gridDim.x * 4) {
        float4 v = *(const float4*)(p + (size_t)r * 256 + c0);
        acc.x += v.x; acc.y += v.y; acc.z += v.z; acc.w += v.w;
    }
    *(float4*)(&part[rg][c0]) = acc;
    __syncthreads();
    if (rg == 0) {
        float4 s = acc;
        for (int r = 1; r < 4; r++) {
            s.x += part[r][c0 + 0]; s.y += part[r][c0 + 1];
            s.z += part[r][c0 + 2]; s.w += part[r][c0 + 3];
        }
        atomicAdd(&g[c0 + 0], s.x);
        atomicAdd(&g[c0 + 1], s.y);
        atomicAdd(&g[c0 + 2], s.z);
        atomicAdd(&g[c0 + 3], s.w);
    }
}

// ---------- MLP head, single block ----------
__global__ __launch_bounds__(256) void mlp_head(const float* __restrict__ g,
                                                const float* __restrict__ Wd1, const float* __restrict__ bd1,
                                                const float* __restrict__ Wd2, const float* __restrict__ bd2,
                                                const float* __restrict__ Wo, const float* __restrict__ bo,
                                                float* __restrict__ out) {
    __shared__ float sg[256], y1[64], y2[32];
    int t = threadIdx.x;
    sg[t] = g[t];
    __syncthreads();
    if (t < 64) {
        float s = bd1[t];
        for (int k = 0; k < 256; k++) s += sg[k] * Wd1[k * 64 + t];
        y1[t] = selu_f(s);
    }
    __syncthreads();
    if (t < 32) {
        float s = bd2[t];
        for (int k = 0; k < 64; k++) s += y1[k] * Wd2[k * 32 + t];
        y2[t] = selu_f(s);
    }
    __syncthreads();
    if (t == 0) {
        float s = bo[0];
        for (int k = 0; k < 32; k++) s += y2[k] * Wo[k];
        out[0] = s;
    }
}

// ---------- host launcher ----------
extern "C" void kernel_launch(void* const* d_in, const int* in_sizes, int n_in,
                              void* d_out, int out_size, void* d_ws, size_t ws_size,
                              hipStream_t stream) {
    const float* x   = (const float*)d_in[0];
    const int*   ei  = (const int*)d_in[1];
    const float* W1  = (const float*)d_in[2];
    const float* as1 = (const float*)d_in[3];
    const float* an1 = (const float*)d_in[4];
    const float* b1  = (const float*)d_in[5];
    const float* W2  = (const float*)d_in[6];
    const float* as2 = (const float*)d_in[7];
    const float* an2 = (const float*)d_in[8];
    const float* b2  = (const float*)d_in[9];
    const float* Wd1 = (const float*)d_in[10];
    const float* bd1 = (const float*)d_in[11];
    const float* Wd2 = (const float*)d_in[12];
    const float* bd2 = (const float*)d_in[13];
    const float* Wo  = (const float*)d_in[14];
    const float* bo  = (const float*)d_in[15];
    const int* tgt  = ei;
    const int* srcp = ei + N_EDGES;

    char* w = (char*)d_ws;
    size_t off_b = 0;
    auto alloc = [&](size_t bytes) -> void* {
        void* p = w + off_b;
        off_b = (off_b + bytes + 255) & ~(size_t)255;
        return p;
    };
    ushort* Bp1  = (ushort*)alloc((size_t)128 * 256 * 2);           // W1 packed
    ushort* Bp2  = (ushort*)alloc((size_t)256 * 256 * 2);           // W2 packed
    unsigned char* xp8 = (unsigned char*)alloc((size_t)N_NODES * 256); // projection, fp8
    ushort* h1b  = (ushort*)alloc((size_t)N_NODES * 256 * 2);       // h1 (bf16)
    float* es    = (float*)alloc((size_t)N_NODES * 4 * 4);
    float* en    = (float*)alloc((size_t)N_NODES * 4 * 4);
    int*   cursor= (int*)alloc((size_t)N_NODES * 4);
    int*   ssrc  = (int*)alloc((size_t)N_NODES * SLOT_CAP * 4);     // slot-CSR (19.2 MB)
    float* pp    = (float*)alloc((size_t)AGG_BLOCKS * 256 * 4);     // layer-2 block partials
    float* g     = (float*)alloc(1024);

    const int EB = (N_EDGES + 255) / 256;  // 3125 scatter blocks
    const int GB = (N_NODES + 63) / 64;    // 782 gemm blocks
    const int T  = EB + GB;

    // ===== slim pack + init (1 launch) =====
    pack_w_init<<<(N_NODES + 255) / 256, 256, 0, stream>>>(W1, Bp1, W2, Bp2, cursor, g);

    // ===== union: slot-CSR scatter + layer-1 gemm, interleaved =====
    scatter_gemm1<<<T, 256, 0, stream>>>(tgt, srcp, cursor, ssrc, N_EDGES, GB, T,
                                         x, (const short8*)Bp1,
                                         xp8, as1, an1, es, en, 16, N_NODES);
    aggregate<<<AGG_BLOCKS, 256, 0, stream>>>(xp8, es, en, cursor, ssrc, b1, h1b, nullptr, N_NODES);

    // ===== layer 2 =====
    gemm_scores<<<GB, 256, 0, stream>>>((const short8*)h1b, (const short8*)Bp2,
                                        xp8, as2, an2, es, en, 32, N_NODES);
    aggregate<<<AGG_BLOCKS, 256, 0, stream>>>(xp8, es, en, cursor, ssrc, b2, nullptr, pp, N_NODES);

    // ===== pool + MLP =====
    colsum_part<<<128, 256, 0, stream>>>(pp, g, AGG_BLOCKS);
    mlp_head<<<1, 256, 0, stream>>>(g, Wd1, bd1, Wd2, bd2, Wo, bo, (float*)d_out);
}

// Round 15
// 271.188 us; speedup vs baseline: 1.3617x; 1.0188x over previous
//
#include <hip/hip_runtime.h>
#include <hip/hip_bf16.h>
#include <hip/hip_fp8.h>
#include <math.h>

#define N_NODES 50000
#define N_EDGES 800000
#define SLOT_CAP 96                     // max in-degree slots per node (E[deg]=16, max<~50)
#define AGG_BLOCKS (N_NODES / 4)        // 12500 aggregate blocks (4 nodes each)

typedef __attribute__((ext_vector_type(8))) short short8;   // 8 x bf16 (4 VGPRs)
typedef __attribute__((ext_vector_type(4))) float f32x4;    // MFMA accumulator
typedef __attribute__((ext_vector_type(2))) float f32x2;

// ---------- device helpers ----------
__device__ __forceinline__ float selu_f(float x) {
    const float scale = 1.0507009873554805f;
    const float alpha = 1.6732632423543772f;
    return x > 0.f ? scale * x : scale * alpha * (expf(x) - 1.f);
}
__device__ __forceinline__ float lrelu_f(float x) {
    return x >= 0.f ? x : 0.2f * x;
}
__device__ __forceinline__ ushort f2bf(float f) {
    __hip_bfloat16 h = __float2bfloat16(f);   // RNE
    return *(ushort*)&h;
}
__device__ __forceinline__ unsigned char f2fp8(float f) {
    __hip_fp8_e4m3 q(f);                       // OCP e4m3, RNE+sat (software fallback)
    return (unsigned char)q.__x;
}
__device__ __forceinline__ float fp82f(unsigned char b) {
    __hip_fp8_e4m3 q; q.__x = (__hip_fp8_storage_t)b;
    return (float)q;
}
// decode 4 packed fp8 (one dword) -> 4 floats
__device__ __forceinline__ void fp8x4_decode(unsigned u, float* o) {
#if __has_builtin(__builtin_amdgcn_cvt_pk_f32_fp8)
    f32x2 lo = __builtin_amdgcn_cvt_pk_f32_fp8((int)u, false);
    f32x2 hi = __builtin_amdgcn_cvt_pk_f32_fp8((int)u, true);
    o[0] = lo.x; o[1] = lo.y; o[2] = hi.x; o[3] = hi.y;
#else
    o[0] = fp82f(u & 0xff);
    o[1] = fp82f((u >> 8) & 0xff);
    o[2] = fp82f((u >> 16) & 0xff);
    o[3] = fp82f(u >> 24);
#endif
}
// encode 4 floats -> packed fp8 dword (HW v_cvt_pk_fp8_f32)
__device__ __forceinline__ unsigned fp8x4_encode(float f0, float f1, float f2, float f3) {
#if __has_builtin(__builtin_amdgcn_cvt_pk_fp8_f32)
    int v = 0;
    v = __builtin_amdgcn_cvt_pk_fp8_f32(f0, f1, v, false);
    v = __builtin_amdgcn_cvt_pk_fp8_f32(f2, f3, v, true);
    return (unsigned)v;
#else
    return (unsigned)f2fp8(f0) | ((unsigned)f2fp8(f1) << 8) |
           ((unsigned)f2fp8(f2) << 16) | ((unsigned)f2fp8(f3) << 24);
#endif
}

// ---------- slim pack + init (once per call): W packing + state zero ----------
__global__ void pack_w_init(const float* __restrict__ W1, ushort* __restrict__ Bp1,
                            const float* __restrict__ W2, ushort* __restrict__ Bp2,
                            int* __restrict__ cursor, float* __restrict__ g) {
    int i = blockIdx.x * blockDim.x + threadIdx.x;
    if (i < 16 * 256) {                     // W1: K8 = 16
        int kg = i >> 8, n = i & 255;
        ushort u[8];
#pragma unroll
        for (int j = 0; j < 8; j++) u[j] = f2bf(W1[(size_t)(kg * 8 + j) * 256 + n]);
        *(uint4*)(Bp1 + ((size_t)kg * 256 + n) * 8) = *(uint4*)u;
    }
    if (i < 32 * 256) {                     // W2: K8 = 32
        int kg = i >> 8, n = i & 255;
        ushort u[8];
#pragma unroll
        for (int j = 0; j < 8; j++) u[j] = f2bf(W2[(size_t)(kg * 8 + j) * 256 + n]);
        *(uint4*)(Bp2 + ((size_t)kg * 256 + n) * 8) = *(uint4*)u;
    }
    if (i < N_NODES) cursor[i] = 0;
    if (i < 256) g[i] = 0.f;
}

// ---------- gemm body (shared by union + standalone kernels) ----------
// 64-row block tile, LDS-staged A (bf16 A, or fp32 Af32 with inline RNE conv),
// fused scores; xp stored fp8.
// Fragment layouts (guide §3, m89/m91-verified): A[m=lane&15][k=quad*8+j],
// B[k=quad*8+j][n=lane&15], D col=lane&15 row=quad*4+reg.
__device__ __forceinline__ void gemm_body(int blk,
                                          const short8* __restrict__ A,
                                          const float* __restrict__ Af32,
                                          const short8* __restrict__ B,
                                          unsigned char* __restrict__ C,
                                          const float* __restrict__ a_self,
                                          const float* __restrict__ a_neigh,
                                          float* __restrict__ es,
                                          float* __restrict__ en,
                                          int K8, int M) {
    __shared__ short8 Atile[64][5];        // [row][chunk 0..3], +1 pad (80B row stride)
    const int tid = threadIdx.x;
    const int wv = tid >> 6, lane = tid & 63;
    const int q = lane >> 4, t = lane & 15;
    const int m0 = blk * 64;
    const int n0 = wv * 64;

    const int srow = tid >> 2, sc = tid & 3;
    int grow = m0 + srow; if (grow > M - 1) grow = M - 1;   // row clamp (stores guarded)
    const short8* Ag = (Af32 == nullptr) ? A + (size_t)grow * K8 + sc : nullptr;
    const float*  Agf = (Af32 != nullptr) ? Af32 + (size_t)grow * (K8 * 8) + sc * 8 : nullptr;

    f32x4 acc[4][4];
#pragma unroll
    for (int mr = 0; mr < 4; mr++)
#pragma unroll
        for (int nc = 0; nc < 4; nc++) acc[mr][nc] = (f32x4){0.f, 0.f, 0.f, 0.f};

    const short8* Bb = B + (size_t)q * 256 + n0 + t;
    for (int kk = 0; kk < K8; kk += 4) {       // 32 k per step
        __syncthreads();
        if (Af32 != nullptr) {                 // block-uniform branch
            float4 v0 = *(const float4*)(Agf + (size_t)kk * 8);
            float4 v1 = *(const float4*)(Agf + (size_t)kk * 8 + 4);
            ushort u[8] = { f2bf(v0.x), f2bf(v0.y), f2bf(v0.z), f2bf(v0.w),
                            f2bf(v1.x), f2bf(v1.y), f2bf(v1.z), f2bf(v1.w) };
            Atile[srow][sc] = *(short8*)u;
        } else {
            Atile[srow][sc] = Ag[kk];
        }
        __syncthreads();
        short8 a0 = Atile[t][q];
        short8 a1 = Atile[16 + t][q];
        short8 a2 = Atile[32 + t][q];
        short8 a3 = Atile[48 + t][q];
        short8 b0 = Bb[(size_t)kk * 256 + 0];
        short8 b1 = Bb[(size_t)kk * 256 + 16];
        short8 b2 = Bb[(size_t)kk * 256 + 32];
        short8 b3 = Bb[(size_t)kk * 256 + 48];
        acc[0][0] = __builtin_amdgcn_mfma_f32_16x16x32_bf16(a0, b0, acc[0][0], 0, 0, 0);
        acc[0][1] = __builtin_amdgcn_mfma_f32_16x16x32_bf16(a0, b1, acc[0][1], 0, 0, 0);
        acc[0][2] = __builtin_amdgcn_mfma_f32_16x16x32_bf16(a0, b2, acc[0][2], 0, 0, 0);
        acc[0][3] = __builtin_amdgcn_mfma_f32_16x16x32_bf16(a0, b3, acc[0][3], 0, 0, 0);
        acc[1][0] = __builtin_amdgcn_mfma_f32_16x16x32_bf16(a1, b0, acc[1][0], 0, 0, 0);
        acc[1][1] = __builtin_amdgcn_mfma_f32_16x16x32_bf16(a1, b1, acc[1][1], 0, 0, 0);
        acc[1][2] = __builtin_amdgcn_mfma_f32_16x16x32_bf16(a1, b2, acc[1][2], 0, 0, 0);
        acc[1][3] = __builtin_amdgcn_mfma_f32_16x16x32_bf16(a1, b3, acc[1][3], 0, 0, 0);
        acc[2][0] = __builtin_amdgcn_mfma_f32_16x16x32_bf16(a2, b0, acc[2][0], 0, 0, 0);
        acc[2][1] = __builtin_amdgcn_mfma_f32_16x16x32_bf16(a2, b1, acc[2][1], 0, 0, 0);
        acc[2][2] = __builtin_amdgcn_mfma_f32_16x16x32_bf16(a2, b2, acc[2][2], 0, 0, 0);
        acc[2][3] = __builtin_amdgcn_mfma_f32_16x16x32_bf16(a2, b3, acc[2][3], 0, 0, 0);
        acc[3][0] = __builtin_amdgcn_mfma_f32_16x16x32_bf16(a3, b0, acc[3][0], 0, 0, 0);
        acc[3][1] = __builtin_amdgcn_mfma_f32_16x16x32_bf16(a3, b1, acc[3][1], 0, 0, 0);
        acc[3][2] = __builtin_amdgcn_mfma_f32_16x16x32_bf16(a3, b2, acc[3][2], 0, 0, 0);
        acc[3][3] = __builtin_amdgcn_mfma_f32_16x16x32_bf16(a3, b3, acc[3][3], 0, 0, 0);
    }

    unsigned char* Cr = C + n0 + t;
#pragma unroll
    for (int mr = 0; mr < 4; mr++) {
#pragma unroll
        for (int r = 0; r < 4; r++) {
            int row = m0 + mr * 16 + q * 4 + r;
            if (row < M) {
                size_t ro = (size_t)row * 256;
                unsigned pk = fp8x4_encode(acc[mr][0][r], acc[mr][1][r],
                                           acc[mr][2][r], acc[mr][3][r]);
                Cr[ro +  0] = (unsigned char)(pk & 0xff);
                Cr[ro + 16] = (unsigned char)((pk >> 8) & 0xff);
                Cr[ro + 32] = (unsigned char)((pk >> 16) & 0xff);
                Cr[ro + 48] = (unsigned char)(pk >> 24);
            }
        }
    }

    float as[4], an[4];
#pragma unroll
    for (int nc = 0; nc < 4; nc++) {
        as[nc] = a_self[n0 + nc * 16 + t];
        an[nc] = a_neigh[n0 + nc * 16 + t];
    }
#pragma unroll
    for (int mr = 0; mr < 4; mr++) {
#pragma unroll
        for (int r = 0; r < 4; r++) {
            float pes = acc[mr][0][r] * as[0] + acc[mr][1][r] * as[1]
                      + acc[mr][2][r] * as[2] + acc[mr][3][r] * as[3];
            float pen = acc[mr][0][r] * an[0] + acc[mr][1][r] * an[1]
                      + acc[mr][2][r] * an[2] + acc[mr][3][r] * an[3];
#pragma unroll
            for (int mask = 1; mask < 16; mask <<= 1) {
                pes += __shfl_xor(pes, mask);
                pen += __shfl_xor(pen, mask);
            }
            if (t == 0) {
                int row = m0 + mr * 16 + q * 4 + r;
                if (row < M) {
                    es[(size_t)row * 4 + wv] = pes;
                    en[(size_t)row * 4 + wv] = pen;
                }
            }
        }
    }
}

// ---------- union kernel: scatter + layer-1 gemm, uniformly interleaved ----------
__global__ __launch_bounds__(256) void scatter_gemm1(const int* __restrict__ tgt,
                                                     const int* __restrict__ src,
                                                     int* __restrict__ cursor,
                                                     int* __restrict__ ssrc, int E,
                                                     int GB, int T,
                                                     const float* __restrict__ x,
                                                     const short8* __restrict__ B,
                                                     unsigned char* __restrict__ C,
                                                     const float* __restrict__ a_self,
                                                     const float* __restrict__ a_neigh,
                                                     float* __restrict__ es,
                                                     float* __restrict__ en,
                                                     int K8, int M) {
    int bid = blockIdx.x;
    int gidx = (int)(((long long)bid * GB) / T);
    int gnext = (int)(((long long)(bid + 1) * GB) / T);
    if (gnext == gidx) {
        int sb = bid - gidx;
        int e = sb * 256 + threadIdx.x;
        if (e < E) {
            int t = tgt[e];
            int r = atomicAdd(&cursor[t], 1);
            if (r < SLOT_CAP) ssrc[(size_t)t * SLOT_CAP + r] = src[e];
        }
        return;
    }
    gemm_body(gidx, nullptr, x, B, C, a_self, a_neigh, es, en, K8, M);
}

// ---------- standalone gemm (layer 2, bf16 A) ----------
__global__ __launch_bounds__(256) void gemm_scores(const short8* __restrict__ A,
                                                   const short8* __restrict__ B,
                                                   unsigned char* __restrict__ C,
                                                   const float* __restrict__ a_self,
                                                   const float* __restrict__ a_neigh,
                                                   float* __restrict__ es,
                                                   float* __restrict__ en,
                                                   int K8, int M) {
    gemm_body(blockIdx.x, A, nullptr, B, C, a_self, a_neigh, es, en, K8, M);
}

// ---------- fused softmax + aggregation: one wave per node, phase-split ----------
// Phase A: lane i (i<deg) gathers en[sv_i] as ONE float4 (deg VMEM insts -> 1)
// and computes all 4 heads' ev (deg wave-wide exps -> 4), storing to per-wave
// LDS (intra-wave: no barrier needed). Phase B: per edge, one ds_read_b32
// broadcast replaces (en-load + exp + lrelu). Identical fp32 values/order.
__global__ __launch_bounds__(256) void aggregate(const unsigned char* __restrict__ xp,
                                                 const float* __restrict__ es,
                                                 const float* __restrict__ en,
                                                 const int* __restrict__ cursor,
                                                 const int* __restrict__ ssrc,
                                                 const float* __restrict__ bias,
                                                 ushort* __restrict__ out,
                                                 float* __restrict__ partials, int N) {
    __shared__ float part[4][256];
    __shared__ float evbuf[4][64][4];       // [wave][edge][head]
    int wave = (blockIdx.x * blockDim.x + threadIdx.x) >> 6;
    int wv = (threadIdx.x >> 6) & 3;
    int lane = threadIdx.x & 63;
    if (wave >= N) return;                  // grid exact: never taken
    int n = wave;
    int e0 = n * SLOT_CAP;
    int deg = cursor[n]; deg = (deg > SLOT_CAP) ? SLOT_CAP : deg;
    int h = lane >> 4;                 // lane's head (channels lane*4..lane*4+3)
    int c0 = lane * 4;

    int dmain = (deg > 64) ? 64 : deg;
    int sv = (lane < dmain) ? ssrc[e0 + lane] : 0;   // whole segment in 1 coalesced load

    // ---- phase A: per-lane parallel en gather + 4-head exp -> LDS ----
    float4 es4 = *(const float4*)(es + (size_t)n * 4);   // wave-uniform
    if (lane < dmain) {
        float4 en4 = *(const float4*)(en + (size_t)sv * 4);
        float4 ev4;
        ev4.x = __expf(lrelu_f(es4.x + en4.x));
        ev4.y = __expf(lrelu_f(es4.y + en4.y));
        ev4.z = __expf(lrelu_f(es4.z + en4.z));
        ev4.w = __expf(lrelu_f(es4.w + en4.w));
        *(float4*)(&evbuf[wv][lane][0]) = ev4;
    }
    // intra-wave LDS dependency only: compiler inserts lgkmcnt wait; no barrier.

    // ---- phase B: per-edge gather + accumulate ----
    float esh = (h == 0) ? es4.x : (h == 1) ? es4.y : (h == 2) ? es4.z : es4.w;
    float dd = 0.f;
    float a0 = 0.f, a1 = 0.f, a2 = 0.f, a3 = 0.f;
    int i = 0;
    for (; i + 3 < dmain; i += 4) {
        int sA = __shfl(sv, i);
        int sB = __shfl(sv, i + 1);
        int sC = __shfl(sv, i + 2);
        int sD = __shfl(sv, i + 3);
        float evA = evbuf[wv][i][h];
        float evB = evbuf[wv][i + 1][h];
        float evC = evbuf[wv][i + 2][h];
        float evD = evbuf[wv][i + 3][h];
        unsigned uA = *(const unsigned*)(xp + (size_t)sA * 256 + c0);
        unsigned uB = *(const unsigned*)(xp + (size_t)sB * 256 + c0);
        unsigned uC = *(const unsigned*)(xp + (size_t)sC * 256 + c0);
        unsigned uD = *(const unsigned*)(xp + (size_t)sD * 256 + c0);
        dd += (evA + evB) + (evC + evD);
        float fA[4], fB[4], fC[4], fD[4];
        fp8x4_decode(uA, fA);
        fp8x4_decode(uB, fB);
        fp8x4_decode(uC, fC);
        fp8x4_decode(uD, fD);
        a0 += evA * fA[0] + evB * fB[0] + evC * fC[0] + evD * fD[0];
        a1 += evA * fA[1] + evB * fB[1] + evC * fC[1] + evD * fD[1];
        a2 += evA * fA[2] + evB * fB[2] + evC * fC[2] + evD * fD[2];
        a3 += evA * fA[3] + evB * fB[3] + evC * fC[3] + evD * fD[3];
    }
    for (; i < dmain; i++) {
        int s = __shfl(sv, i);
        float ev = evbuf[wv][i][h];
        unsigned u = *(const unsigned*)(xp + (size_t)s * 256 + c0);
        dd += ev;
        float f[4];
        fp8x4_decode(u, f);
        a0 += ev * f[0]; a1 += ev * f[1]; a2 += ev * f[2]; a3 += ev * f[3];
    }
    // tail: deg > 64 (statistically absent at Poisson(16); correctness guard)
    for (int e = e0 + 64; e < e0 + deg; e++) {
        int s = __builtin_amdgcn_readfirstlane(ssrc[e]);
        float ev = __expf(lrelu_f(esh + en[(size_t)s * 4 + h]));
        unsigned u = *(const unsigned*)(xp + (size_t)s * 256 + c0);
        dd += ev;
        float f[4];
        fp8x4_decode(u, f);
        a0 += ev * f[0]; a1 += ev * f[1]; a2 += ev * f[2]; a3 += ev * f[3];
    }

    float inv = (dd > 0.f) ? 1.f / dd : 0.f;
    float4 bb = *(const float4*)(bias + c0);
    float r0 = selu_f(a0 * inv + bb.x);
    float r1 = selu_f(a1 * inv + bb.y);
    float r2 = selu_f(a2 * inv + bb.z);
    float r3 = selu_f(a3 * inv + bb.w);
    if (partials == nullptr) {
        ushort r[4] = { f2bf(r0), f2bf(r1), f2bf(r2), f2bf(r3) };
        *(uint2*)(out + (size_t)n * 256 + c0) = *(uint2*)r;
    } else {
        part[wv][c0 + 0] = r0; part[wv][c0 + 1] = r1;
        part[wv][c0 + 2] = r2; part[wv][c0 + 3] = r3;
        __syncthreads();
        if (wv == 0) {
            float4 s;
            s.x = r0 + part[1][c0 + 0] + part[2][c0 + 0] + part[3][c0 + 0];
            s.y = r1 + part[1][c0 + 1] + part[2][c0 + 1] + part[3][c0 + 1];
            s.z = r2 + part[1][c0 + 2] + part[2][c0 + 2] + part[3][c0 + 2];
            s.w = r3 + part[1][c0 + 3] + part[2][c0 + 3] + part[3][c0 + 3];
            *(float4*)(partials + (size_t)blockIdx.x * 256 + c0) = s;
        }
    }
}

// ---------- reduce per-block partials [R][256] -> g[256] ----------
__global__ __launch_bounds__(256) void colsum_part(const float* __restrict__ p,
                                                   float* __restrict__ g, int R) {
    __shared__ float part[4][256];
    int tid = threadIdx.x;
    int rg = tid >> 6;            // row group 0..3
    int c0 = (tid & 63) * 4;      // channel group
    float4 acc = {0.f, 0.f, 0.f, 0.f};
    for (int r = blockIdx.x * 4 + rg; r < R; r += gridDim.x * 4) {
        float4 v = *(const float4*)(p + (size_t)r * 256 + c0);
        acc.x += v.x; acc.y += v.y; acc.z += v.z; acc.w += v.w;
    }
    *(float4*)(&part[rg][c0]) = acc;
    __syncthreads();
    if (rg == 0) {
        float4 s = acc;
        for (int r = 1; r < 4; r++) {
            s.x += part[r][c0 + 0]; s.y += part[r][c0 + 1];
            s.z += part[r][c0 + 2]; s.w += part[r][c0 + 3];
        }
        atomicAdd(&g[c0 + 0], s.x);
        atomicAdd(&g[c0 + 1], s.y);
        atomicAdd(&g[c0 + 2], s.z);
        atomicAdd(&g[c0 + 3], s.w);
    }
}

// ---------- MLP head, single block ----------
__global__ __launch_bounds__(256) void mlp_head(const float* __restrict__ g,
                                                const float* __restrict__ Wd1, const float* __restrict__ bd1,
                                                const float* __restrict__ Wd2, const float* __restrict__ bd2,
                                                const float* __restrict__ Wo, const float* __restrict__ bo,
                                                float* __restrict__ out) {
    __shared__ float sg[256], y1[64], y2[32];
    int t = threadIdx.x;
    sg[t] = g[t];
    __syncthreads();
    if (t < 64) {
        float s = bd1[t];
        for (int k = 0; k < 256; k++) s += sg[k] * Wd1[k * 64 + t];
        y1[t] = selu_f(s);
    }
    __syncthreads();
    if (t < 32) {
        float s = bd2[t];
        for (int k = 0; k < 64; k++) s += y1[k] * Wd2[k * 32 + t];
        y2[t] = selu_f(s);
    }
    __syncthreads();
    if (t == 0) {
        float s = bo[0];
        for (int k = 0; k < 32; k++) s += y2[k] * Wo[k];
        out[0] = s;
    }
}

// ---------- host launcher ----------
extern "C" void kernel_launch(void* const* d_in, const int* in_sizes, int n_in,
                              void* d_out, int out_size, void* d_ws, size_t ws_size,
                              hipStream_t stream) {
    const float* x   = (const float*)d_in[0];
    const int*   ei  = (const int*)d_in[1];
    const float* W1  = (const float*)d_in[2];
    const float* as1 = (const float*)d_in[3];
    const float* an1 = (const float*)d_in[4];
    const float* b1  = (const float*)d_in[5];
    const float* W2  = (const float*)d_in[6];
    const float* as2 = (const float*)d_in[7];
    const float* an2 = (const float*)d_in[8];
    const float* b2  = (const float*)d_in[9];
    const float* Wd1 = (const float*)d_in[10];
    const float* bd1 = (const float*)d_in[11];
    const float* Wd2 = (const float*)d_in[12];
    const float* bd2 = (const float*)d_in[13];
    const float* Wo  = (const float*)d_in[14];
    const float* bo  = (const float*)d_in[15];
    const int* tgt  = ei;
    const int* srcp = ei + N_EDGES;

    char* w = (char*)d_ws;
    size_t off_b = 0;
    auto alloc = [&](size_t bytes) -> void* {
        void* p = w + off_b;
        off_b = (off_b + bytes + 255) & ~(size_t)255;
        return p;
    };
    ushort* Bp1  = (ushort*)alloc((size_t)128 * 256 * 2);           // W1 packed
    ushort* Bp2  = (ushort*)alloc((size_t)256 * 256 * 2);           // W2 packed
    unsigned char* xp8 = (unsigned char*)alloc((size_t)N_NODES * 256); // projection, fp8
    ushort* h1b  = (ushort*)alloc((size_t)N_NODES * 256 * 2);       // h1 (bf16)
    float* es    = (float*)alloc((size_t)N_NODES * 4 * 4);
    float* en    = (float*)alloc((size_t)N_NODES * 4 * 4);
    int*   cursor= (int*)alloc((size_t)N_NODES * 4);
    int*   ssrc  = (int*)alloc((size_t)N_NODES * SLOT_CAP * 4);     // slot-CSR (19.2 MB)
    float* pp    = (float*)alloc((size_t)AGG_BLOCKS * 256 * 4);     // layer-2 block partials
    float* g     = (float*)alloc(1024);

    const int EB = (N_EDGES + 255) / 256;  // 3125 scatter blocks
    const int GB = (N_NODES + 63) / 64;    // 782 gemm blocks
    const int T  = EB + GB;

    // ===== slim pack + init (1 launch) =====
    pack_w_init<<<(N_NODES + 255) / 256, 256, 0, stream>>>(W1, Bp1, W2, Bp2, cursor, g);

    // ===== union: slot-CSR scatter + layer-1 gemm, interleaved =====
    scatter_gemm1<<<T, 256, 0, stream>>>(tgt, srcp, cursor, ssrc, N_EDGES, GB, T,
                                         x, (const short8*)Bp1,
                                         xp8, as1, an1, es, en, 16, N_NODES);
    aggregate<<<AGG_BLOCKS, 256, 0, stream>>>(xp8, es, en, cursor, ssrc, b1, h1b, nullptr, N_NODES);

    // ===== layer 2 =====
    gemm_scores<<<GB, 256, 0, stream>>>((const short8*)h1b, (const short8*)Bp2,
                                        xp8, as2, an2, es, en, 32, N_NODES);
    aggregate<<<AGG_BLOCKS, 256, 0, stream>>>(xp8, es, en, cursor, ssrc, b2, nullptr, pp, N_NODES);

    // ===== pool + MLP =====
    colsum_part<<<128, 256, 0, stream>>>(pp, g, AGG_BLOCKS);
    mlp_head<<<1, 256, 0, stream>>>(g, Wd1, bd1, Wd2, bd2, Wo, bo, (float*)d_out);
}